// Round 1
// 526.939 us; speedup vs baseline: 1.0956x; 1.0956x over previous
//
#include <hip/hip_runtime.h>
#include <math.h>

#define N_NODES 40000
#define M_PAD   40064      // 313 * 128
#define N_EDGES 640000
#define D       256
#define H       8
#define DFF     1024
#define D3      768
#define ATT_SCALE 0.0625f  // 256^-0.5
#define LN_EPS  1e-5f

typedef __attribute__((ext_vector_type(8))) short short8;
typedef __attribute__((ext_vector_type(4))) float f32x4;

__device__ __forceinline__ unsigned short f2bf(float f) {
    unsigned int u = __builtin_bit_cast(unsigned int, f);
    u = (u + 0x7FFF + ((u >> 16) & 1)) >> 16;   // RTNE
    return (unsigned short)u;
}
__device__ __forceinline__ float bf2f(unsigned short u) {
    return __builtin_bit_cast(float, (unsigned int)u << 16);
}

// ---------------------------------------------------------------------------
// LayerNorm -> bf16 output in MFMA A-fragment order [M/16][D/8][16][8].
// One wave per row; lane covers cols lane*4..lane*4+3.
// ---------------------------------------------------------------------------
__global__ __launch_bounds__(256) void ln_bf_kernel(const float* __restrict__ in,
                                                    const float* __restrict__ g,
                                                    const float* __restrict__ b,
                                                    unsigned short* __restrict__ out)
{
    const int row  = blockIdx.x * 4 + (threadIdx.x >> 6);
    const int lane = threadIdx.x & 63;
    const float4 v = *reinterpret_cast<const float4*>(in + (size_t)row * D + lane * 4);
    float s  = v.x + v.y + v.z + v.w;
    float s2 = v.x * v.x + v.y * v.y + v.z * v.z + v.w * v.w;
#pragma unroll
    for (int o = 32; o > 0; o >>= 1) {
        s  += __shfl_xor(s,  o, 64);
        s2 += __shfl_xor(s2, o, 64);
    }
    const float mu  = s * (1.0f / D);
    const float var = s2 * (1.0f / D) - mu * mu;
    const float rs  = rsqrtf(var + LN_EPS);
    const float4 gg = *reinterpret_cast<const float4*>(g + lane * 4);
    const float4 bb = *reinterpret_cast<const float4*>(b + lane * 4);
    ushort4 o4;
    o4.x = f2bf((v.x - mu) * rs * gg.x + bb.x);
    o4.y = f2bf((v.y - mu) * rs * gg.y + bb.y);
    o4.z = f2bf((v.z - mu) * rs * gg.z + bb.z);
    o4.w = f2bf((v.w - mu) * rs * gg.w + bb.w);
    // fragment order: mt=row>>4, kc=lane>>1, mi=row&15, ki=(lane&1)*4
    const size_t off = (((size_t)(row >> 4) * (D / 8) + (lane >> 1)) * 16 + (row & 15)) * 8
                       + (lane & 1) * 4;
    *reinterpret_cast<ushort4*>(out + off) = o4;
}

// ---------------------------------------------------------------------------
// Weight pack: W[K][N] fp32 -> bf16 packed [N/16][K/8][16][8].
// ---------------------------------------------------------------------------
template <int K, int N>
__global__ __launch_bounds__(256) void pack_w_kernel(const float* __restrict__ W,
                                                     unsigned short* __restrict__ Wpk)
{
    const int idx = blockIdx.x * 256 + threadIdx.x;   // [N/16][K/8][16]
    const int ni  = idx & 15;
    const int kc  = (idx >> 4) % (K / 8);
    const int nt  = idx / (16 * (K / 8));
    const int n   = nt * 16 + ni;
    unsigned short o[8];
#pragma unroll
    for (int i = 0; i < 8; ++i)
        o[i] = f2bf(W[(size_t)(kc * 8 + i) * N + n]);
    *reinterpret_cast<short8*>(Wpk + (size_t)idx * 8) = *reinterpret_cast<short8*>(o);
}

// ---------------------------------------------------------------------------
// bf16 MFMA GEMM, both operands pre-packed fragment order -- NO LDS, no
// barriers: fragments are loaded global->VGPR directly (perfectly coalesced,
// 1 KB/wave per dwordx4; B is L2-resident, A streamed).
// MFMA operands are SWAPPED: mfma(bf, af, acc) so D maps to
//   activation row r = lane&15, weight cols n = (lane>>4)*4 + t
// giving each thread 4 CONSECUTIVE output columns -> vectorized epilogue.
// A: [M/16][K/8][16][8]   B: [N/16][K/8][16][8]
// Block 256 thr = 4 waves; 128x128 tile.
// EPI 0: bf16 C row-major, scale cols<256 by ATT_SCALE (qkv), ushort4 stores
// EPI 1: bf16 C in fragment order [M/16][N/8][16][8] + exact gelu, ushort4
// EPI 2: fp32 C row-major += Xadd, float4 load+store
// ---------------------------------------------------------------------------
template <int EPI, int K, int N>
__global__ __launch_bounds__(256) void mfma_gemm_kernel(const unsigned short* __restrict__ A,
                                                        const unsigned short* __restrict__ Bpk,
                                                        const float* __restrict__ bias,
                                                        void* __restrict__ Cout,
                                                        const float* __restrict__ Xadd)
{
    const int tid  = threadIdx.x;
    const int wave = tid >> 6;
    const int lane = tid & 63;
    const int row0 = blockIdx.y * 128;
    const int col0 = blockIdx.x * 128;
    const int wm   = (wave >> 1) * 64;
    const int wn   = (wave & 1) * 64;
    const int g    = lane >> 4;     // k-chunk selector in frag; col quad in D
    const int q    = lane & 15;     // m/n index in frag; row in D

    f32x4 acc[4][4] = {};

    const size_t tstride = (size_t)(K / 8) * 128;   // shorts per 16-row tile
    const unsigned short* pA = A   + ((size_t)((row0 + wm) >> 4) * (K / 8) + g) * 128 + q * 8;
    const unsigned short* pB = Bpk + ((size_t)((col0 + wn) >> 4) * (K / 8) + g) * 128 + q * 8;

#pragma unroll 2
    for (int kq = 0; kq < K / 8; kq += 4) {         // one 16x16x32 MFMA = 4 k-chunks
        short8 af[4], bfr[4];
#pragma unroll
        for (int i = 0; i < 4; ++i) {
            af[i]  = *reinterpret_cast<const short8*>(pA + i * tstride + (size_t)kq * 128);
            bfr[i] = *reinterpret_cast<const short8*>(pB + i * tstride + (size_t)kq * 128);
        }
#pragma unroll
        for (int i = 0; i < 4; ++i)
#pragma unroll
            for (int j = 0; j < 4; ++j)
                acc[i][j] = __builtin_amdgcn_mfma_f32_16x16x32_bf16(bfr[j], af[i], acc[i][j], 0, 0, 0);
    }

    // Swapped D layout: r = row0+wm+i*16+q ; n = col0+wn+j*16+g*4+t (t=0..3)
#pragma unroll
    for (int i = 0; i < 4; ++i) {
        const int r = row0 + wm + i * 16 + q;
        if (r >= N_NODES) continue;
#pragma unroll
        for (int j = 0; j < 4; ++j) {
            const int nb = col0 + wn + j * 16 + g * 4;
            const float4 bz = *reinterpret_cast<const float4*>(bias + nb);
            float o0 = acc[i][j][0] + bz.x;
            float o1 = acc[i][j][1] + bz.y;
            float o2 = acc[i][j][2] + bz.z;
            float o3 = acc[i][j][3] + bz.w;
            if (EPI == 0) {
                if (nb < 256) { o0 *= ATT_SCALE; o1 *= ATT_SCALE; o2 *= ATT_SCALE; o3 *= ATT_SCALE; }
                ushort4 u;
                u.x = f2bf(o0); u.y = f2bf(o1); u.z = f2bf(o2); u.w = f2bf(o3);
                *reinterpret_cast<ushort4*>((unsigned short*)Cout + (size_t)r * N + nb) = u;
            } else if (EPI == 1) {
                o0 = 0.5f * o0 * (1.0f + erff(o0 * 0.70710678118654752f));
                o1 = 0.5f * o1 * (1.0f + erff(o1 * 0.70710678118654752f));
                o2 = 0.5f * o2 * (1.0f + erff(o2 * 0.70710678118654752f));
                o3 = 0.5f * o3 * (1.0f + erff(o3 * 0.70710678118654752f));
                // fragment order for next GEMM's A; nb&7 = (g&1)*4 -> 8B aligned
                const size_t off = (((size_t)(r >> 4) * (N / 8) + (nb >> 3)) * 16
                                    + (r & 15)) * 8 + (nb & 7);
                ushort4 u;
                u.x = f2bf(o0); u.y = f2bf(o1); u.z = f2bf(o2); u.w = f2bf(o3);
                *reinterpret_cast<ushort4*>((unsigned short*)Cout + off) = u;
            } else {
                const float4 xd = *reinterpret_cast<const float4*>(Xadd + (size_t)r * N + nb);
                float4 ov;
                ov.x = o0 + xd.x; ov.y = o1 + xd.y; ov.z = o2 + xd.z; ov.w = o3 + xd.w;
                *reinterpret_cast<float4*>((float*)Cout + (size_t)r * N + nb) = ov;
            }
        }
    }
}

// ---------------------------------------------------------------------------
// CSR build: histogram -> single-block scan (1024 thr, writes rowptr AND
// cursor, kills the D2D memcpy) -> fill
// ---------------------------------------------------------------------------
__global__ __launch_bounds__(256) void hist_kernel(const int* __restrict__ dst,
                                                   int* __restrict__ counts)
{
    const int i = blockIdx.x * 256 + threadIdx.x;
    atomicAdd(&counts[dst[i]], 1);
}

__global__ __launch_bounds__(1024) void scan_kernel(const int* __restrict__ counts,
                                                    int* __restrict__ rowptr,
                                                    int* __restrict__ cursor)
{
    const int PER = 40;                    // 1024*40 = 40960 >= N_NODES
    const int tid  = threadIdx.x;
    const int base = tid * PER;
    int c[PER];
    int s = 0;
#pragma unroll
    for (int i = 0; i < PER; ++i) {
        const int idx = base + i;
        c[i] = (idx < N_NODES) ? counts[idx] : 0;
        s += c[i];
    }
    __shared__ int sm[1024];
    sm[tid] = s;
    __syncthreads();
    for (int off = 1; off < 1024; off <<= 1) {
        int t = (tid >= off) ? sm[tid - off] : 0;
        __syncthreads();
        sm[tid] += t;
        __syncthreads();
    }
    int run = sm[tid] - s;
#pragma unroll
    for (int i = 0; i < PER; ++i) {
        const int idx = base + i;
        if (idx < N_NODES) {
            rowptr[idx] = run;
            cursor[idx] = run;
            run += c[i];
        }
    }
    if (tid == 1023) rowptr[N_NODES] = sm[1023];
}

__global__ __launch_bounds__(256) void fill_kernel(const int* __restrict__ src,
                                                   const int* __restrict__ dst,
                                                   int* __restrict__ cursor,
                                                   int* __restrict__ srcs)
{
    const int e = blockIdx.x * 256 + threadIdx.x;
    const int pos = atomicAdd(&cursor[dst[e]], 1);
    if (pos >= 0 && pos < N_EDGES) srcs[pos] = src[e];
}

// ---------------------------------------------------------------------------
// Fused attention: score + single-pass softmax + aggregate + residual + LN2.
// One wave per dst node. The node's src list is prefetched into a lane
// register (one coalesced load), broadcast via v_readlane (scalar gather
// addresses), 4-edge unroll -> 8 independent gathers in flight.
// Outputs: x fp32 row-major, xn bf16 in fragment order.
// ---------------------------------------------------------------------------
__global__ __launch_bounds__(256) void fused_attn_kernel(const unsigned short* __restrict__ qkv,
                                                         const int* __restrict__ srcs,
                                                         const int* __restrict__ rowptr,
                                                         const float* __restrict__ triplet_h,
                                                         const float* __restrict__ g,
                                                         const float* __restrict__ b,
                                                         float* __restrict__ x,
                                                         unsigned short* __restrict__ xn)
{
    const int node = blockIdx.x * 4 + (threadIdx.x >> 6);
    const int lane = threadIdx.x & 63;
    int beg = rowptr[node];
    int end = rowptr[node + 1];
    beg = max(0, min(beg, N_EDGES));
    end = max(beg, min(end, N_EDGES));
    const int deg = end - beg;

    const ushort4 ku = *reinterpret_cast<const ushort4*>(
        qkv + (size_t)node * D3 + 256 + lane * 4);
    const float k0 = bf2f(ku.x), k1 = bf2f(ku.y), k2 = bf2f(ku.z), k3 = bf2f(ku.w);

    float dsum = 0.0f;
    float4 acc = {0.0f, 0.0f, 0.0f, 0.0f};

    for (int base = 0; base < deg; base += 64) {    // one iter for deg<=64 (typ. ~16)
        const int cnt = min(64, deg - base);
        const int idx = base + lane;
        const int sv = (idx < deg) ? srcs[beg + idx] : 0;   // coalesced prefetch
        int j = 0;
        for (; j + 4 <= cnt; j += 4) {
            const int s0 = __builtin_amdgcn_readlane(sv, j);
            const int s1 = __builtin_amdgcn_readlane(sv, j + 1);
            const int s2 = __builtin_amdgcn_readlane(sv, j + 2);
            const int s3 = __builtin_amdgcn_readlane(sv, j + 3);
            const ushort4 qa = *reinterpret_cast<const ushort4*>(qkv + (size_t)s0 * D3 + lane * 4);
            const ushort4 qb = *reinterpret_cast<const ushort4*>(qkv + (size_t)s1 * D3 + lane * 4);
            const ushort4 qc = *reinterpret_cast<const ushort4*>(qkv + (size_t)s2 * D3 + lane * 4);
            const ushort4 qd = *reinterpret_cast<const ushort4*>(qkv + (size_t)s3 * D3 + lane * 4);
            const ushort4 va = *reinterpret_cast<const ushort4*>(qkv + (size_t)s0 * D3 + 512 + lane * 4);
            const ushort4 vb = *reinterpret_cast<const ushort4*>(qkv + (size_t)s1 * D3 + 512 + lane * 4);
            const ushort4 vc = *reinterpret_cast<const ushort4*>(qkv + (size_t)s2 * D3 + 512 + lane * 4);
            const ushort4 vd = *reinterpret_cast<const ushort4*>(qkv + (size_t)s3 * D3 + 512 + lane * 4);
            float p0 = bf2f(qa.x) * k0 + bf2f(qa.y) * k1 + bf2f(qa.z) * k2 + bf2f(qa.w) * k3;
            float p1 = bf2f(qb.x) * k0 + bf2f(qb.y) * k1 + bf2f(qb.z) * k2 + bf2f(qb.w) * k3;
            float p2 = bf2f(qc.x) * k0 + bf2f(qc.y) * k1 + bf2f(qc.z) * k2 + bf2f(qc.w) * k3;
            float p3 = bf2f(qd.x) * k0 + bf2f(qd.y) * k1 + bf2f(qd.z) * k2 + bf2f(qd.w) * k3;
            p0 += __shfl_xor(p0, 1, 64); p1 += __shfl_xor(p1, 1, 64);
            p2 += __shfl_xor(p2, 1, 64); p3 += __shfl_xor(p3, 1, 64);
            p0 += __shfl_xor(p0, 2, 64); p1 += __shfl_xor(p1, 2, 64);
            p2 += __shfl_xor(p2, 2, 64); p3 += __shfl_xor(p3, 2, 64);
            p0 += __shfl_xor(p0, 4, 64); p1 += __shfl_xor(p1, 4, 64);
            p2 += __shfl_xor(p2, 4, 64); p3 += __shfl_xor(p3, 4, 64);
            const float w0 = __expf(p0), w1 = __expf(p1), w2 = __expf(p2), w3 = __expf(p3);
            acc.x += w0 * bf2f(va.x) + w1 * bf2f(vb.x) + w2 * bf2f(vc.x) + w3 * bf2f(vd.x);
            acc.y += w0 * bf2f(va.y) + w1 * bf2f(vb.y) + w2 * bf2f(vc.y) + w3 * bf2f(vd.y);
            acc.z += w0 * bf2f(va.z) + w1 * bf2f(vb.z) + w2 * bf2f(vc.z) + w3 * bf2f(vd.z);
            acc.w += w0 * bf2f(va.w) + w1 * bf2f(vb.w) + w2 * bf2f(vc.w) + w3 * bf2f(vd.w);
            dsum += (w0 + w1) + (w2 + w3);
        }
        for (; j < cnt; ++j) {
            const int s0 = __builtin_amdgcn_readlane(sv, j);
            const ushort4 qa = *reinterpret_cast<const ushort4*>(qkv + (size_t)s0 * D3 + lane * 4);
            const ushort4 va = *reinterpret_cast<const ushort4*>(qkv + (size_t)s0 * D3 + 512 + lane * 4);
            float p0 = bf2f(qa.x) * k0 + bf2f(qa.y) * k1 + bf2f(qa.z) * k2 + bf2f(qa.w) * k3;
            p0 += __shfl_xor(p0, 1, 64);
            p0 += __shfl_xor(p0, 2, 64);
            p0 += __shfl_xor(p0, 4, 64);
            const float w0 = __expf(p0);
            acc.x += w0 * bf2f(va.x);
            acc.y += w0 * bf2f(va.y);
            acc.z += w0 * bf2f(va.z);
            acc.w += w0 * bf2f(va.w);
            dsum += w0;
        }
    }
    const float inv = (deg > 0) ? 1.0f / dsum : 0.0f;

    const float4 th = *reinterpret_cast<const float4*>(
        triplet_h + (size_t)node * D + lane * 4);
    float4 xv;
    xv.x = th.x + acc.x * inv;
    xv.y = th.y + acc.y * inv;
    xv.z = th.z + acc.z * inv;
    xv.w = th.w + acc.w * inv;
    *reinterpret_cast<float4*>(x + (size_t)node * D + lane * 4) = xv;

    // LN2 across the wave
    float s  = xv.x + xv.y + xv.z + xv.w;
    float s2 = xv.x * xv.x + xv.y * xv.y + xv.z * xv.z + xv.w * xv.w;
#pragma unroll
    for (int o = 32; o > 0; o >>= 1) {
        s  += __shfl_xor(s,  o, 64);
        s2 += __shfl_xor(s2, o, 64);
    }
    const float mu  = s * (1.0f / D);
    const float var = s2 * (1.0f / D) - mu * mu;
    const float rs  = rsqrtf(var + LN_EPS);
    const float4 gg = *reinterpret_cast<const float4*>(g + lane * 4);
    const float4 bb = *reinterpret_cast<const float4*>(b + lane * 4);
    ushort4 o4;
    o4.x = f2bf((xv.x - mu) * rs * gg.x + bb.x);
    o4.y = f2bf((xv.y - mu) * rs * gg.y + bb.y);
    o4.z = f2bf((xv.z - mu) * rs * gg.z + bb.z);
    o4.w = f2bf((xv.w - mu) * rs * gg.w + bb.w);
    const size_t off = (((size_t)(node >> 4) * (D / 8) + (lane >> 1)) * 16 + (node & 15)) * 8
                       + (lane & 1) * 4;
    *reinterpret_cast<ushort4*>(xn + off) = o4;
}

// ---------------------------------------------------------------------------
extern "C" void kernel_launch(void* const* d_in, const int* in_sizes, int n_in,
                              void* d_out, int out_size, void* d_ws, size_t ws_size,
                              hipStream_t stream)
{
    const float* triplet_h = (const float*)d_in[0];
    const int*   src       = (const int*)d_in[1];
    const int*   dst       = (const int*)d_in[2];
    const float* Wqkv      = (const float*)d_in[3];
    const float* bqkv      = (const float*)d_in[4];
    const float* ln_attn_g = (const float*)d_in[5];
    const float* ln_attn_b = (const float*)d_in[6];
    const float* ln_res_g  = (const float*)d_in[7];
    const float* ln_res_b  = (const float*)d_in[8];
    const float* W_in      = (const float*)d_in[9];
    const float* b_in      = (const float*)d_in[10];
    const float* W_out     = (const float*)d_in[11];
    const float* b_out     = (const float*)d_in[12];
    float* out = (float*)d_out;

    // Workspace (~150 MB, well under proven 245.76 MB ceiling):
    char* w = (char*)d_ws;
    unsigned short* bufA = (unsigned short*)w;   // qkv bf16 row-major OR a1 bf16 frag
    w += (size_t)M_PAD * DFF * sizeof(unsigned short);
    unsigned short* h_xn = (unsigned short*)w;  w += (size_t)M_PAD * D * sizeof(unsigned short);
    float*          x    = (float*)w;           w += (size_t)N_NODES * D * sizeof(float);
    unsigned short* Wqkv_pk = (unsigned short*)w; w += (size_t)D * D3 * sizeof(unsigned short);
    unsigned short* Win_pk  = (unsigned short*)w; w += (size_t)D * DFF * sizeof(unsigned short);
    unsigned short* Wout_pk = (unsigned short*)w; w += (size_t)DFF * D * sizeof(unsigned short);
    int* counts = (int*)w;  w += (size_t)N_NODES * sizeof(int);
    int* rowptr = (int*)w;  w += (size_t)(N_NODES + 1) * sizeof(int);
    int* cursor = (int*)w;  w += (size_t)N_NODES * sizeof(int);
    int* srcs   = (int*)w;  w += (size_t)N_EDGES * sizeof(int);

    unsigned short* qkv = bufA;  // [40000][768] bf16 row-major, dead after fused_attn
    unsigned short* a1  = bufA;  // [M_PAD/16][128][16][8] bf16 frag, live FFN only

    // ---- CSR build ----
    hipMemsetAsync(counts, 0, (size_t)N_NODES * sizeof(int), stream);
    hist_kernel<<<N_EDGES / 256, 256, 0, stream>>>(dst, counts);
    scan_kernel<<<1, 1024, 0, stream>>>(counts, rowptr, cursor);
    fill_kernel<<<N_EDGES / 256, 256, 0, stream>>>(src, dst, cursor, srcs);

    // ---- weight packing ----
    pack_w_kernel<D,  D3 ><<<(D * D3 / 8) / 256, 256, 0, stream>>>(Wqkv, Wqkv_pk);
    pack_w_kernel<D,  DFF><<<(D * DFF / 8) / 256, 256, 0, stream>>>(W_in, Win_pk);
    pack_w_kernel<DFF, D ><<<(DFF * D / 8) / 256, 256, 0, stream>>>(W_out, Wout_pk);

    // h/xn pad rows (mt tiles 2500..2503) -> zero; frag region is byte-identical
    // to rows [40000,40064) x 256.
    hipMemsetAsync(h_xn + (size_t)N_NODES * D, 0,
                   (size_t)(M_PAD - N_NODES) * D * sizeof(unsigned short), stream);

    // ---- main pipeline ----
    ln_bf_kernel<<<N_NODES / 4, 256, 0, stream>>>(triplet_h, ln_attn_g, ln_attn_b, h_xn);
    mfma_gemm_kernel<0, D, D3><<<dim3(D3 / 128, M_PAD / 128), 256, 0, stream>>>(
        h_xn, Wqkv_pk, bqkv, qkv, nullptr);
    fused_attn_kernel<<<N_NODES / 4, 256, 0, stream>>>(qkv, srcs, rowptr, triplet_h,
                                                       ln_res_g, ln_res_b, x, h_xn);
    // qkv dead; zero a1 pad region (frag: byte-identical to rows [40000,40064) x 1024)
    hipMemsetAsync(a1 + (size_t)N_NODES * DFF, 0,
                   (size_t)(M_PAD - N_NODES) * DFF * sizeof(unsigned short), stream);
    mfma_gemm_kernel<1, D, DFF><<<dim3(DFF / 128, M_PAD / 128), 256, 0, stream>>>(
        h_xn, Win_pk, b_in, a1, nullptr);
    mfma_gemm_kernel<2, DFF, D><<<dim3(D / 128, M_PAD / 128), 256, 0, stream>>>(
        a1, Wout_pk, b_out, out, x);

    (void)in_sizes; (void)n_in; (void)out_size; (void)ws_size;
}

// Round 3
// 455.404 us; speedup vs baseline: 1.2677x; 1.1571x over previous
//
#include <hip/hip_runtime.h>
#include <math.h>

#define N_NODES 40000
#define M_PAD   40064      // 313 * 128
#define N_EDGES 640000
#define D       256
#define H       8
#define DFF     1024
#define D3      768
#define ATT_SCALE 0.0625f  // 256^-0.5
#define LN_EPS  1e-5f

typedef __attribute__((ext_vector_type(8))) short short8;
typedef __attribute__((ext_vector_type(4))) float f32x4;
typedef __attribute__((ext_vector_type(2))) float f32x2;

__device__ __forceinline__ unsigned short f2bf(float f) {
    unsigned int u = __builtin_bit_cast(unsigned int, f);
    u = (u + 0x7FFF + ((u >> 16) & 1)) >> 16;   // RTNE
    return (unsigned short)u;
}
__device__ __forceinline__ float bf2f(unsigned short u) {
    return __builtin_bit_cast(float, (unsigned int)u << 16);
}

// ---------------- fp8 e4m3 pack/unpack (HW cvt on gfx950, SW fallback) -----
#if __has_builtin(__builtin_amdgcn_cvt_pk_fp8_f32) && __has_builtin(__builtin_amdgcn_cvt_pk_f32_fp8)
#define HW_FP8 1
#else
#define HW_FP8 0
__device__ __forceinline__ unsigned char enc_e4m3(float f) {
    unsigned int u = __builtin_bit_cast(unsigned int, f);
    unsigned int s = (u >> 24) & 0x80;
    float a = fabsf(f);
    if (a >= 0x1p-6f) {
        unsigned int bits = __builtin_bit_cast(unsigned int, a);
        unsigned int q = bits >> 20;
        unsigned int rem = bits & 0xFFFFFu;
        q += (rem > 0x80000u) || ((rem == 0x80000u) && (q & 1));
        q -= 960;                          // rebias (120<<3)
        if (q > 126) q = 126;              // clamp to 448
        return (unsigned char)(s | q);
    }
    float t = a * 512.0f;
    unsigned int r = (unsigned int)rintf(t);   // RNE; 8 -> min normal naturally
    return (unsigned char)(s | r);
}
__device__ __forceinline__ float dec_e4m3(unsigned int v) {
    unsigned int em = v & 0x7f;
    float n = __builtin_bit_cast(float, (em << 20) + 0x3C000000u);
    float r = (em >= 8) ? n : (float)em * 0x1p-9f;
    return (v & 0x80) ? -r : r;
}
#endif

__device__ __forceinline__ unsigned int pack4_e4m3(float a, float b, float c, float d) {
#if HW_FP8
    unsigned int w = (unsigned int)__builtin_amdgcn_cvt_pk_fp8_f32(a, b, 0, false);
    w = (unsigned int)__builtin_amdgcn_cvt_pk_fp8_f32(c, d, (int)w, true);
    return w;
#else
    return (unsigned int)enc_e4m3(a) | ((unsigned int)enc_e4m3(b) << 8)
         | ((unsigned int)enc_e4m3(c) << 16) | ((unsigned int)enc_e4m3(d) << 24);
#endif
}
__device__ __forceinline__ void dec4_e4m3(unsigned int w, float& a, float& b, float& c, float& d) {
#if HW_FP8
    f32x2 lo = __builtin_amdgcn_cvt_pk_f32_fp8((int)w, false);
    f32x2 hi = __builtin_amdgcn_cvt_pk_f32_fp8((int)w, true);
    a = lo[0]; b = lo[1]; c = hi[0]; d = hi[1];
#else
    a = dec_e4m3(w & 0xff); b = dec_e4m3((w >> 8) & 0xff);
    c = dec_e4m3((w >> 16) & 0xff); d = dec_e4m3(w >> 24);
#endif
}

// ---------------------------------------------------------------------------
// LayerNorm -> bf16 output in MFMA A-fragment order [M/16][D/8][16][8].
// Covers pad rows [N_NODES, M_PAD) with zeros (replaces a memset).
// ---------------------------------------------------------------------------
__global__ __launch_bounds__(256) void ln_bf_kernel(const float* __restrict__ in,
                                                    const float* __restrict__ g,
                                                    const float* __restrict__ b,
                                                    unsigned short* __restrict__ out)
{
    const int row  = blockIdx.x * 4 + (threadIdx.x >> 6);
    const int lane = threadIdx.x & 63;
    const size_t off = (((size_t)(row >> 4) * (D / 8) + (lane >> 1)) * 16 + (row & 15)) * 8
                       + (lane & 1) * 4;
    if (row >= N_NODES) {
        ushort4 z = {0, 0, 0, 0};
        *reinterpret_cast<ushort4*>(out + off) = z;
        return;
    }
    const float4 v = *reinterpret_cast<const float4*>(in + (size_t)row * D + lane * 4);
    float s  = v.x + v.y + v.z + v.w;
    float s2 = v.x * v.x + v.y * v.y + v.z * v.z + v.w * v.w;
#pragma unroll
    for (int o = 32; o > 0; o >>= 1) {
        s  += __shfl_xor(s,  o, 64);
        s2 += __shfl_xor(s2, o, 64);
    }
    const float mu  = s * (1.0f / D);
    const float var = s2 * (1.0f / D) - mu * mu;
    const float rs  = rsqrtf(var + LN_EPS);
    const float4 gg = *reinterpret_cast<const float4*>(g + lane * 4);
    const float4 bb = *reinterpret_cast<const float4*>(b + lane * 4);
    ushort4 o4;
    o4.x = f2bf((v.x - mu) * rs * gg.x + bb.x);
    o4.y = f2bf((v.y - mu) * rs * gg.y + bb.y);
    o4.z = f2bf((v.z - mu) * rs * gg.z + bb.z);
    o4.w = f2bf((v.w - mu) * rs * gg.w + bb.w);
    *reinterpret_cast<ushort4*>(out + off) = o4;
}

// ---------------------------------------------------------------------------
// Weight pack: W[K][N] fp32 -> bf16 packed [N/16][K/8][16][8]. All three
// weights in ONE kernel (one launch).
// ---------------------------------------------------------------------------
template <int K, int N>
__device__ __forceinline__ void pack_body(const float* __restrict__ W,
                                          unsigned short* __restrict__ Wpk, int blk)
{
    const int idx = blk * 256 + threadIdx.x;   // [N/16][K/8][16]
    const int ni  = idx & 15;
    const int kc  = (idx >> 4) % (K / 8);
    const int nt  = idx / (16 * (K / 8));
    const int n   = nt * 16 + ni;
    unsigned short o[8];
#pragma unroll
    for (int i = 0; i < 8; ++i)
        o[i] = f2bf(W[(size_t)(kc * 8 + i) * N + n]);
    *reinterpret_cast<short8*>(Wpk + (size_t)idx * 8) = *reinterpret_cast<short8*>(o);
}

__global__ __launch_bounds__(256) void pack_all_kernel(const float* __restrict__ Wqkv,
                                                       const float* __restrict__ W_in,
                                                       const float* __restrict__ W_out,
                                                       unsigned short* __restrict__ pq,
                                                       unsigned short* __restrict__ pi,
                                                       unsigned short* __restrict__ po)
{
    const int b = blockIdx.x;
    if (b < 96)       pack_body<D, D3 >(Wqkv, pq, b);
    else if (b < 224) pack_body<D, DFF>(W_in, pi, b - 96);
    else              pack_body<DFF, D>(W_out, po, b - 224);
}

// ---------------------------------------------------------------------------
// bf16 MFMA GEMM, both operands pre-packed fragment order. Direct global->
// VGPR operand loads (no LDS), explicit peeled double-buffer (2 operand
// groups, no register copies), __launch_bounds__(256,3) -> 3 blocks/CU.
// Panel-colocating XCD swizzle: all col-blocks of a 128-row panel map to the
// same XCD (bid%8), so the A panel is fetched into that L2 once.
// MFMA operands SWAPPED: D maps to row r = lane&15, cols n = (lane>>4)*4+t.
// EPI 0: qkv split -> q (cols<256) unscaled fp8 e4m3, k|v bf16 row-major
// EPI 1: bf16 C in fragment order [M/16][N/8][16][8] + exact gelu (all rows)
// EPI 2: fp32 C row-major += Xadd, nontemporal f32x4 store
// ---------------------------------------------------------------------------
template <int EPI, int K, int N>
__global__ __launch_bounds__(256, 3) void mfma_gemm_kernel(const unsigned short* __restrict__ A,
                                                           const unsigned short* __restrict__ Bpk,
                                                           const float* __restrict__ bias,
                                                           void* __restrict__ Cout,
                                                           void* __restrict__ Cout2,
                                                           const float* __restrict__ Xadd)
{
    constexpr int C  = N / 128;          // col tiles
    constexpr int P  = M_PAD / 128;      // 313 row panels
    constexpr int NG = K / 32;           // MFMA k-groups (8 or 32, even)

    const int bid = blockIdx.x;
    const int xcd = bid & 7;
    const int t   = bid >> 3;
    const int c   = t % C;
    const int p   = (t / C) * 8 + xcd;
    if (p >= P) return;

    const int tid  = threadIdx.x;
    const int wave = tid >> 6;
    const int lane = tid & 63;
    const int row0 = p * 128;
    const int col0 = c * 128;
    const int wm   = (wave >> 1) * 64;
    const int wn   = (wave & 1) * 64;
    const int g    = lane >> 4;
    const int q    = lane & 15;

    f32x4 acc[4][4] = {};

    constexpr size_t tstride = (size_t)(K / 8) * 128;   // shorts per 16-row tile
    const unsigned short* pA = A   + ((size_t)((row0 + wm) >> 4) * (K / 8) + g) * 128 + q * 8;
    const unsigned short* pB = Bpk + ((size_t)((col0 + wn) >> 4) * (K / 8) + g) * 128 + q * 8;

    short8 aA[4], bA[4], aB[4], bB[4];
#pragma unroll
    for (int i = 0; i < 4; ++i) {      // group 0 -> buf A
        aA[i] = *reinterpret_cast<const short8*>(pA + i * tstride);
        bA[i] = *reinterpret_cast<const short8*>(pB + i * tstride);
    }
#pragma unroll
    for (int i = 0; i < 4; ++i) {      // group 1 -> buf B
        aB[i] = *reinterpret_cast<const short8*>(pA + i * tstride + 512);
        bB[i] = *reinterpret_cast<const short8*>(pB + i * tstride + 512);
    }

#pragma unroll 1
    for (int g2 = 0; g2 < NG / 2 - 1; ++g2) {
#pragma unroll
        for (int i = 0; i < 4; ++i)
#pragma unroll
            for (int j = 0; j < 4; ++j)
                acc[i][j] = __builtin_amdgcn_mfma_f32_16x16x32_bf16(bA[j], aA[i], acc[i][j], 0, 0, 0);
#pragma unroll
        for (int i = 0; i < 4; ++i) {  // group 2*g2+2 -> buf A
            aA[i] = *reinterpret_cast<const short8*>(pA + i * tstride + (size_t)(g2 * 8 + 8) * 128);
            bA[i] = *reinterpret_cast<const short8*>(pB + i * tstride + (size_t)(g2 * 8 + 8) * 128);
        }
#pragma unroll
        for (int i = 0; i < 4; ++i)
#pragma unroll
            for (int j = 0; j < 4; ++j)
                acc[i][j] = __builtin_amdgcn_mfma_f32_16x16x32_bf16(bB[j], aB[i], acc[i][j], 0, 0, 0);
#pragma unroll
        for (int i = 0; i < 4; ++i) {  // group 2*g2+3 -> buf B
            aB[i] = *reinterpret_cast<const short8*>(pA + i * tstride + (size_t)(g2 * 8 + 12) * 128);
            bB[i] = *reinterpret_cast<const short8*>(pB + i * tstride + (size_t)(g2 * 8 + 12) * 128);
        }
    }
#pragma unroll
    for (int i = 0; i < 4; ++i)
#pragma unroll
        for (int j = 0; j < 4; ++j)
            acc[i][j] = __builtin_amdgcn_mfma_f32_16x16x32_bf16(bA[j], aA[i], acc[i][j], 0, 0, 0);
#pragma unroll
    for (int i = 0; i < 4; ++i)
#pragma unroll
        for (int j = 0; j < 4; ++j)
            acc[i][j] = __builtin_amdgcn_mfma_f32_16x16x32_bf16(bB[j], aB[i], acc[i][j], 0, 0, 0);

    // Swapped D layout: r = row0+wm+i*16+q ; n = col0+wn+j*16+g*4+t (t=0..3)
    if constexpr (EPI == 0) {
        if (col0 < 256) {   // q columns -> fp8, UNSCALED (scale folded into k at attn)
            unsigned char* q8 = (unsigned char*)Cout;
#pragma unroll
            for (int i = 0; i < 4; ++i) {
                const int r = row0 + wm + i * 16 + q;
                if (r >= N_NODES) continue;
#pragma unroll
                for (int j = 0; j < 4; ++j) {
                    const int nb = col0 + wn + j * 16 + g * 4;
                    const float4 bz = *reinterpret_cast<const float4*>(bias + nb);
                    const unsigned int w = pack4_e4m3(acc[i][j][0] + bz.x, acc[i][j][1] + bz.y,
                                                      acc[i][j][2] + bz.z, acc[i][j][3] + bz.w);
                    *reinterpret_cast<unsigned int*>(q8 + (size_t)r * 256 + nb) = w;
                }
            }
        } else {            // k|v columns -> bf16 row-major [node][512]
            unsigned short* kv = (unsigned short*)Cout2;
#pragma unroll
            for (int i = 0; i < 4; ++i) {
                const int r = row0 + wm + i * 16 + q;
                if (r >= N_NODES) continue;
#pragma unroll
                for (int j = 0; j < 4; ++j) {
                    const int nb = col0 + wn + j * 16 + g * 4;
                    const float4 bz = *reinterpret_cast<const float4*>(bias + nb);
                    ushort4 u;
                    u.x = f2bf(acc[i][j][0] + bz.x);
                    u.y = f2bf(acc[i][j][1] + bz.y);
                    u.z = f2bf(acc[i][j][2] + bz.z);
                    u.w = f2bf(acc[i][j][3] + bz.w);
                    *reinterpret_cast<ushort4*>(kv + (size_t)r * 512 + (nb - 256)) = u;
                }
            }
        }
    } else if constexpr (EPI == 1) {
#pragma unroll
        for (int i = 0; i < 4; ++i) {
            const int r = row0 + wm + i * 16 + q;   // pad rows stored too (finite)
#pragma unroll
            for (int j = 0; j < 4; ++j) {
                const int nb = col0 + wn + j * 16 + g * 4;
                const float4 bz = *reinterpret_cast<const float4*>(bias + nb);
                float o0 = acc[i][j][0] + bz.x;
                float o1 = acc[i][j][1] + bz.y;
                float o2 = acc[i][j][2] + bz.z;
                float o3 = acc[i][j][3] + bz.w;
                o0 = 0.5f * o0 * (1.0f + erff(o0 * 0.70710678118654752f));
                o1 = 0.5f * o1 * (1.0f + erff(o1 * 0.70710678118654752f));
                o2 = 0.5f * o2 * (1.0f + erff(o2 * 0.70710678118654752f));
                o3 = 0.5f * o3 * (1.0f + erff(o3 * 0.70710678118654752f));
                const size_t off = (((size_t)(r >> 4) * (N / 8) + (nb >> 3)) * 16
                                    + (r & 15)) * 8 + (nb & 7);
                ushort4 u;
                u.x = f2bf(o0); u.y = f2bf(o1); u.z = f2bf(o2); u.w = f2bf(o3);
                *reinterpret_cast<ushort4*>((unsigned short*)Cout + off) = u;
            }
        }
    } else {
#pragma unroll
        for (int i = 0; i < 4; ++i) {
            const int r = row0 + wm + i * 16 + q;
            if (r >= N_NODES) continue;
#pragma unroll
            for (int j = 0; j < 4; ++j) {
                const int nb = col0 + wn + j * 16 + g * 4;
                const float4 bz = *reinterpret_cast<const float4*>(bias + nb);
                const float4 xd = *reinterpret_cast<const float4*>(Xadd + (size_t)r * N + nb);
                f32x4 ov;
                ov[0] = acc[i][j][0] + bz.x + xd.x;
                ov[1] = acc[i][j][1] + bz.y + xd.y;
                ov[2] = acc[i][j][2] + bz.z + xd.z;
                ov[3] = acc[i][j][3] + bz.w + xd.w;
                __builtin_nontemporal_store(ov,
                    reinterpret_cast<f32x4*>((float*)Cout + (size_t)r * N + nb));
            }
        }
    }
}

// ---------------------------------------------------------------------------
// CSR build
// ---------------------------------------------------------------------------
__global__ __launch_bounds__(256) void hist_kernel(const int* __restrict__ dst,
                                                   int* __restrict__ counts)
{
    const int i = blockIdx.x * 256 + threadIdx.x;
    atomicAdd(&counts[dst[i]], 1);
}

__global__ __launch_bounds__(1024) void scan_kernel(const int* __restrict__ counts,
                                                    int* __restrict__ rowptr,
                                                    int* __restrict__ cursor)
{
    const int PER = 40;
    const int tid  = threadIdx.x;
    const int base = tid * PER;
    int c[PER];
    int s = 0;
#pragma unroll
    for (int i = 0; i < PER; ++i) {
        const int idx = base + i;
        c[i] = (idx < N_NODES) ? counts[idx] : 0;
        s += c[i];
    }
    __shared__ int sm[1024];
    sm[tid] = s;
    __syncthreads();
    for (int off = 1; off < 1024; off <<= 1) {
        int t = (tid >= off) ? sm[tid - off] : 0;
        __syncthreads();
        sm[tid] += t;
        __syncthreads();
    }
    int run = sm[tid] - s;
#pragma unroll
    for (int i = 0; i < PER; ++i) {
        const int idx = base + i;
        if (idx < N_NODES) {
            rowptr[idx] = run;
            cursor[idx] = run;
            run += c[i];
        }
    }
    if (tid == 1023) rowptr[N_NODES] = sm[1023];
}

__global__ __launch_bounds__(256) void fill_kernel(const int* __restrict__ src,
                                                   const int* __restrict__ dst,
                                                   int* __restrict__ cursor,
                                                   int* __restrict__ srcs)
{
    const int e = blockIdx.x * 256 + threadIdx.x;
    const int pos = atomicAdd(&cursor[dst[e]], 1);
    if (pos >= 0 && pos < N_EDGES) srcs[pos] = src[e];
}

// ---------------------------------------------------------------------------
// Fused attention: q fp8 (256 B/row) + k|v bf16 (1024 B/row, pow2 stride).
// One wave per dst node; src list coalesce-prefetched, readlane broadcast,
// 4-edge unroll. k scaled by ATT_SCALE at load (q stored unscaled).
// Outputs: x fp32 row-major, xn bf16 in fragment order.
// ---------------------------------------------------------------------------
__global__ __launch_bounds__(256) void fused_attn_kernel(const unsigned char* __restrict__ qf8,
                                                         const unsigned short* __restrict__ kv,
                                                         const int* __restrict__ srcs,
                                                         const int* __restrict__ rowptr,
                                                         const float* __restrict__ triplet_h,
                                                         const float* __restrict__ g,
                                                         const float* __restrict__ b,
                                                         float* __restrict__ x,
                                                         unsigned short* __restrict__ xn)
{
    const int node = blockIdx.x * 4 + (threadIdx.x >> 6);
    const int lane = threadIdx.x & 63;
    int beg = rowptr[node];
    int end = rowptr[node + 1];
    beg = max(0, min(beg, N_EDGES));
    end = max(beg, min(end, N_EDGES));
    const int deg = end - beg;

    const ushort4 ku = *reinterpret_cast<const ushort4*>(
        kv + (size_t)node * 512 + lane * 4);
    const float k0 = bf2f(ku.x) * ATT_SCALE, k1 = bf2f(ku.y) * ATT_SCALE;
    const float k2 = bf2f(ku.z) * ATT_SCALE, k3 = bf2f(ku.w) * ATT_SCALE;

    float dsum = 0.0f;
    float4 acc = {0.0f, 0.0f, 0.0f, 0.0f};

    for (int base = 0; base < deg; base += 64) {
        const int cnt = min(64, deg - base);
        const int idx = base + lane;
        const int sv = (idx < deg) ? srcs[beg + idx] : 0;   // coalesced prefetch
        int j = 0;
        for (; j + 4 <= cnt; j += 4) {
            const int s0 = __builtin_amdgcn_readlane(sv, j);
            const int s1 = __builtin_amdgcn_readlane(sv, j + 1);
            const int s2 = __builtin_amdgcn_readlane(sv, j + 2);
            const int s3 = __builtin_amdgcn_readlane(sv, j + 3);
            const unsigned int qa = *reinterpret_cast<const unsigned int*>(qf8 + (size_t)s0 * 256 + lane * 4);
            const unsigned int qb = *reinterpret_cast<const unsigned int*>(qf8 + (size_t)s1 * 256 + lane * 4);
            const unsigned int qc = *reinterpret_cast<const unsigned int*>(qf8 + (size_t)s2 * 256 + lane * 4);
            const unsigned int qd = *reinterpret_cast<const unsigned int*>(qf8 + (size_t)s3 * 256 + lane * 4);
            const ushort4 va = *reinterpret_cast<const ushort4*>(kv + (size_t)s0 * 512 + 256 + lane * 4);
            const ushort4 vb = *reinterpret_cast<const ushort4*>(kv + (size_t)s1 * 512 + 256 + lane * 4);
            const ushort4 vc = *reinterpret_cast<const ushort4*>(kv + (size_t)s2 * 512 + 256 + lane * 4);
            const ushort4 vd = *reinterpret_cast<const ushort4*>(kv + (size_t)s3 * 512 + 256 + lane * 4);
            float a0, a1, a2, a3;
            dec4_e4m3(qa, a0, a1, a2, a3);
            float p0 = a0 * k0 + a1 * k1 + a2 * k2 + a3 * k3;
            dec4_e4m3(qb, a0, a1, a2, a3);
            float p1 = a0 * k0 + a1 * k1 + a2 * k2 + a3 * k3;
            dec4_e4m3(qc, a0, a1, a2, a3);
            float p2 = a0 * k0 + a1 * k1 + a2 * k2 + a3 * k3;
            dec4_e4m3(qd, a0, a1, a2, a3);
            float p3 = a0 * k0 + a1 * k1 + a2 * k2 + a3 * k3;
            p0 += __shfl_xor(p0, 1, 64); p1 += __shfl_xor(p1, 1, 64);
            p2 += __shfl_xor(p2, 1, 64); p3 += __shfl_xor(p3, 1, 64);
            p0 += __shfl_xor(p0, 2, 64); p1 += __shfl_xor(p1, 2, 64);
            p2 += __shfl_xor(p2, 2, 64); p3 += __shfl_xor(p3, 2, 64);
            p0 += __shfl_xor(p0, 4, 64); p1 += __shfl_xor(p1, 4, 64);
            p2 += __shfl_xor(p2, 4, 64); p3 += __shfl_xor(p3, 4, 64);
            const float w0 = __expf(p0), w1 = __expf(p1), w2 = __expf(p2), w3 = __expf(p3);
            acc.x += w0 * bf2f(va.x) + w1 * bf2f(vb.x) + w2 * bf2f(vc.x) + w3 * bf2f(vd.x);
            acc.y += w0 * bf2f(va.y) + w1 * bf2f(vb.y) + w2 * bf2f(vc.y) + w3 * bf2f(vd.y);
            acc.z += w0 * bf2f(va.z) + w1 * bf2f(vb.z) + w2 * bf2f(vc.z) + w3 * bf2f(vd.z);
            acc.w += w0 * bf2f(va.w) + w1 * bf2f(vb.w) + w2 * bf2f(vc.w) + w3 * bf2f(vd.w);
            dsum += (w0 + w1) + (w2 + w3);
        }
        for (; j < cnt; ++j) {
            const int s0 = __builtin_amdgcn_readlane(sv, j);
            const unsigned int qa = *reinterpret_cast<const unsigned int*>(qf8 + (size_t)s0 * 256 + lane * 4);
            const ushort4 va = *reinterpret_cast<const ushort4*>(kv + (size_t)s0 * 512 + 256 + lane * 4);
            float a0, a1, a2, a3;
            dec4_e4m3(qa, a0, a1, a2, a3);
            float p0 = a0 * k0 + a1 * k1 + a2 * k2 + a3 * k3;
            p0 += __shfl_xor(p0, 1, 64);
            p0 += __shfl_xor(p0, 2, 64);
            p0 += __shfl_xor(p0, 4, 64);
            const float w0 = __expf(p0);
            acc.x += w0 * bf2f(va.x);
            acc.y += w0 * bf2f(va.y);
            acc.z += w0 * bf2f(va.z);
            acc.w += w0 * bf2f(va.w);
            dsum += w0;
        }
    }
    const float inv = (deg > 0) ? 1.0f / dsum : 0.0f;

    const float4 th = *reinterpret_cast<const float4*>(
        triplet_h + (size_t)node * D + lane * 4);
    float4 xv;
    xv.x = th.x + acc.x * inv;
    xv.y = th.y + acc.y * inv;
    xv.z = th.z + acc.z * inv;
    xv.w = th.w + acc.w * inv;
    *reinterpret_cast<float4*>(x + (size_t)node * D + lane * 4) = xv;

    // LN2 across the wave
    float s  = xv.x + xv.y + xv.z + xv.w;
    float s2 = xv.x * xv.x + xv.y * xv.y + xv.z * xv.z + xv.w * xv.w;
#pragma unroll
    for (int o = 32; o > 0; o >>= 1) {
        s  += __shfl_xor(s,  o, 64);
        s2 += __shfl_xor(s2, o, 64);
    }
    const float mu  = s * (1.0f / D);
    const float var = s2 * (1.0f / D) - mu * mu;
    const float rs  = rsqrtf(var + LN_EPS);
    const float4 gg = *reinterpret_cast<const float4*>(g + lane * 4);
    const float4 bb = *reinterpret_cast<const float4*>(b + lane * 4);
    ushort4 o4;
    o4.x = f2bf((xv.x - mu) * rs * gg.x + bb.x);
    o4.y = f2bf((xv.y - mu) * rs * gg.y + bb.y);
    o4.z = f2bf((xv.z - mu) * rs * gg.z + bb.z);
    o4.w = f2bf((xv.w - mu) * rs * gg.w + bb.w);
    const size_t off = (((size_t)(node >> 4) * (D / 8) + (lane >> 1)) * 16 + (node & 15)) * 8
                       + (lane & 1) * 4;
    *reinterpret_cast<ushort4*>(xn + off) = o4;
}

// ---------------------------------------------------------------------------
extern "C" void kernel_launch(void* const* d_in, const int* in_sizes, int n_in,
                              void* d_out, int out_size, void* d_ws, size_t ws_size,
                              hipStream_t stream)
{
    const float* triplet_h = (const float*)d_in[0];
    const int*   src       = (const int*)d_in[1];
    const int*   dst       = (const int*)d_in[2];
    const float* Wqkv      = (const float*)d_in[3];
    const float* bqkv      = (const float*)d_in[4];
    const float* ln_attn_g = (const float*)d_in[5];
    const float* ln_attn_b = (const float*)d_in[6];
    const float* ln_res_g  = (const float*)d_in[7];
    const float* ln_res_b  = (const float*)d_in[8];
    const float* W_in      = (const float*)d_in[9];
    const float* b_in      = (const float*)d_in[10];
    const float* W_out     = (const float*)d_in[11];
    const float* b_out     = (const float*)d_in[12];
    float* out = (float*)d_out;

    // Workspace (~162 MB, under 245.76 MB ceiling):
    char* w = (char*)d_ws;
    unsigned short* bufA = (unsigned short*)w;   // kv bf16 row-major OR a1 bf16 frag
    w += (size_t)M_PAD * DFF * sizeof(unsigned short);
    unsigned short* h_xn = (unsigned short*)w;  w += (size_t)M_PAD * D * sizeof(unsigned short);
    float*          x    = (float*)w;           w += (size_t)N_NODES * D * sizeof(float);
    unsigned char*  qf8  = (unsigned char*)w;   w += (size_t)N_NODES * 256;
    unsigned short* Wqkv_pk = (unsigned short*)w; w += (size_t)D * D3 * sizeof(unsigned short);
    unsigned short* Win_pk  = (unsigned short*)w; w += (size_t)D * DFF * sizeof(unsigned short);
    unsigned short* Wout_pk = (unsigned short*)w; w += (size_t)DFF * D * sizeof(unsigned short);
    int* counts = (int*)w;  w += (size_t)N_NODES * sizeof(int);
    int* rowptr = (int*)w;  w += (size_t)(N_NODES + 1) * sizeof(int);
    int* cursor = (int*)w;  w += (size_t)N_NODES * sizeof(int);
    int* srcs   = (int*)w;  w += (size_t)N_EDGES * sizeof(int);

    unsigned short* kv = bufA;  // [40000][512] bf16 (k|v), dead after fused_attn
    unsigned short* a1 = bufA;  // [M_PAD/16][128][16][8] bf16 frag, live FFN only

    // ---- CSR build ----
    (void)hipMemsetAsync(counts, 0, (size_t)N_NODES * sizeof(int), stream);
    hist_kernel<<<N_EDGES / 256, 256, 0, stream>>>(dst, counts);
    scan_kernel<<<1, 1024, 0, stream>>>(counts, rowptr, cursor);
    fill_kernel<<<N_EDGES / 256, 256, 0, stream>>>(src, dst, cursor, srcs);

    // ---- weight packing (one launch) ----
    pack_all_kernel<<<352, 256, 0, stream>>>(Wqkv, W_in, W_out, Wqkv_pk, Win_pk, Wout_pk);

    // ---- main pipeline ----
    ln_bf_kernel<<<M_PAD / 4, 256, 0, stream>>>(triplet_h, ln_attn_g, ln_attn_b, h_xn);
    mfma_gemm_kernel<0, D, D3><<<((M_PAD / 128 + 7) / 8) * 8 * (D3 / 128), 256, 0, stream>>>(
        h_xn, Wqkv_pk, bqkv, qf8, kv, nullptr);
    fused_attn_kernel<<<N_NODES / 4, 256, 0, stream>>>(qf8, kv, srcs, rowptr, triplet_h,
                                                       ln_res_g, ln_res_b, x, h_xn);
    // kv dead; a1 overwrites it (EPI1 stores pad rows too -> no memset needed)
    mfma_gemm_kernel<1, D, DFF><<<((M_PAD / 128 + 7) / 8) * 8 * (DFF / 128), 256, 0, stream>>>(
        h_xn, Win_pk, b_in, a1, nullptr, nullptr);
    mfma_gemm_kernel<2, DFF, D><<<((M_PAD / 128 + 7) / 8) * 8 * (D / 128), 256, 0, stream>>>(
        a1, Wout_pk, b_out, out, nullptr, x);

    (void)in_sizes; (void)n_in; (void)out_size; (void)ws_size;
}

// Round 4
// 447.601 us; speedup vs baseline: 1.2898x; 1.0174x over previous
//
#include <hip/hip_runtime.h>
#include <math.h>

#define N_NODES 40000
#define M_PAD   40064      // 313 * 128
#define N_EDGES 640000
#define D       256
#define H       8
#define DFF     1024
#define D3      768
#define ATT_SCALE 0.0625f  // 256^-0.5
#define LN_EPS  1e-5f

typedef __attribute__((ext_vector_type(8))) short short8;
typedef __attribute__((ext_vector_type(4))) float f32x4;
typedef __attribute__((ext_vector_type(2))) float f32x2;

__device__ __forceinline__ unsigned short f2bf(float f) {
    unsigned int u = __builtin_bit_cast(unsigned int, f);
    u = (u + 0x7FFF + ((u >> 16) & 1)) >> 16;   // RTNE
    return (unsigned short)u;
}
__device__ __forceinline__ float bf2f(unsigned short u) {
    return __builtin_bit_cast(float, (unsigned int)u << 16);
}

// Fast exact-gelu: Abramowitz-Stegun 7.1.26 erf (|eps| <= 1.5e-7, branchless).
// ~16 VALU + v_rcp + v_exp vs libm erff's ~40+ ops.
__device__ __forceinline__ float fast_gelu(float x) {
    const float z  = fabsf(x) * 0.70710678118654752f;
    const float t  = __builtin_amdgcn_rcpf(1.0f + 0.3275911f * z);
    float p = 1.061405429f;
    p = p * t - 1.453152027f;
    p = p * t + 1.421413741f;
    p = p * t - 0.284496736f;
    p = p * t + 0.254829592f;
    const float e  = __expf(-z * z);
    const float ea = 1.0f - p * t * e;          // erf(|x|/sqrt2)
    const float er = (x < 0.0f) ? -ea : ea;
    return 0.5f * x * (1.0f + er);
}

// ---------------- fp8 e4m3 pack/unpack (HW cvt on gfx950, SW fallback) -----
#if __has_builtin(__builtin_amdgcn_cvt_pk_fp8_f32) && __has_builtin(__builtin_amdgcn_cvt_pk_f32_fp8)
#define HW_FP8 1
#else
#define HW_FP8 0
__device__ __forceinline__ unsigned char enc_e4m3(float f) {
    unsigned int u = __builtin_bit_cast(unsigned int, f);
    unsigned int s = (u >> 24) & 0x80;
    float a = fabsf(f);
    if (a >= 0x1p-6f) {
        unsigned int bits = __builtin_bit_cast(unsigned int, a);
        unsigned int q = bits >> 20;
        unsigned int rem = bits & 0xFFFFFu;
        q += (rem > 0x80000u) || ((rem == 0x80000u) && (q & 1));
        q -= 960;                          // rebias (120<<3)
        if (q > 126) q = 126;              // clamp to 448
        return (unsigned char)(s | q);
    }
    float t = a * 512.0f;
    unsigned int r = (unsigned int)rintf(t);   // RNE; 8 -> min normal naturally
    return (unsigned char)(s | r);
}
__device__ __forceinline__ float dec_e4m3(unsigned int v) {
    unsigned int em = v & 0x7f;
    float n = __builtin_bit_cast(float, (em << 20) + 0x3C000000u);
    float r = (em >= 8) ? n : (float)em * 0x1p-9f;
    return (v & 0x80) ? -r : r;
}
#endif

__device__ __forceinline__ unsigned int pack4_e4m3(float a, float b, float c, float d) {
#if HW_FP8
    unsigned int w = (unsigned int)__builtin_amdgcn_cvt_pk_fp8_f32(a, b, 0, false);
    w = (unsigned int)__builtin_amdgcn_cvt_pk_fp8_f32(c, d, (int)w, true);
    return w;
#else
    return (unsigned int)enc_e4m3(a) | ((unsigned int)enc_e4m3(b) << 8)
         | ((unsigned int)enc_e4m3(c) << 16) | ((unsigned int)enc_e4m3(d) << 24);
#endif
}
__device__ __forceinline__ void dec4_e4m3(unsigned int w, float& a, float& b, float& c, float& d) {
#if HW_FP8
    f32x2 lo = __builtin_amdgcn_cvt_pk_f32_fp8((int)w, false);
    f32x2 hi = __builtin_amdgcn_cvt_pk_f32_fp8((int)w, true);
    a = lo[0]; b = lo[1]; c = hi[0]; d = hi[1];
#else
    a = dec_e4m3(w & 0xff); b = dec_e4m3((w >> 8) & 0xff);
    c = dec_e4m3((w >> 16) & 0xff); d = dec_e4m3(w >> 24);
#endif
}

// ---------------------------------------------------------------------------
// LayerNorm -> bf16 output in MFMA A-fragment order [M/16][D/8][16][8].
// Covers pad rows [N_NODES, M_PAD) with zeros (replaces a memset).
// ---------------------------------------------------------------------------
__global__ __launch_bounds__(256) void ln_bf_kernel(const float* __restrict__ in,
                                                    const float* __restrict__ g,
                                                    const float* __restrict__ b,
                                                    unsigned short* __restrict__ out)
{
    const int row  = blockIdx.x * 4 + (threadIdx.x >> 6);
    const int lane = threadIdx.x & 63;
    const size_t off = (((size_t)(row >> 4) * (D / 8) + (lane >> 1)) * 16 + (row & 15)) * 8
                       + (lane & 1) * 4;
    if (row >= N_NODES) {
        ushort4 z = {0, 0, 0, 0};
        *reinterpret_cast<ushort4*>(out + off) = z;
        return;
    }
    const float4 v = *reinterpret_cast<const float4*>(in + (size_t)row * D + lane * 4);
    float s  = v.x + v.y + v.z + v.w;
    float s2 = v.x * v.x + v.y * v.y + v.z * v.z + v.w * v.w;
#pragma unroll
    for (int o = 32; o > 0; o >>= 1) {
        s  += __shfl_xor(s,  o, 64);
        s2 += __shfl_xor(s2, o, 64);
    }
    const float mu  = s * (1.0f / D);
    const float var = s2 * (1.0f / D) - mu * mu;
    const float rs  = rsqrtf(var + LN_EPS);
    const float4 gg = *reinterpret_cast<const float4*>(g + lane * 4);
    const float4 bb = *reinterpret_cast<const float4*>(b + lane * 4);
    ushort4 o4;
    o4.x = f2bf((v.x - mu) * rs * gg.x + bb.x);
    o4.y = f2bf((v.y - mu) * rs * gg.y + bb.y);
    o4.z = f2bf((v.z - mu) * rs * gg.z + bb.z);
    o4.w = f2bf((v.w - mu) * rs * gg.w + bb.w);
    *reinterpret_cast<ushort4*>(out + off) = o4;
}

// ---------------------------------------------------------------------------
// Weight pack: W[K][N] fp32 -> bf16 packed [N/16][K/8][16][8]. All three
// weights in ONE kernel (one launch).
// ---------------------------------------------------------------------------
template <int K, int N>
__device__ __forceinline__ void pack_body(const float* __restrict__ W,
                                          unsigned short* __restrict__ Wpk, int blk)
{
    const int idx = blk * 256 + threadIdx.x;   // [N/16][K/8][16]
    const int ni  = idx & 15;
    const int kc  = (idx >> 4) % (K / 8);
    const int nt  = idx / (16 * (K / 8));
    const int n   = nt * 16 + ni;
    unsigned short o[8];
#pragma unroll
    for (int i = 0; i < 8; ++i)
        o[i] = f2bf(W[(size_t)(kc * 8 + i) * N + n]);
    *reinterpret_cast<short8*>(Wpk + (size_t)idx * 8) = *reinterpret_cast<short8*>(o);
}

__global__ __launch_bounds__(256) void pack_all_kernel(const float* __restrict__ Wqkv,
                                                       const float* __restrict__ W_in,
                                                       const float* __restrict__ W_out,
                                                       unsigned short* __restrict__ pq,
                                                       unsigned short* __restrict__ pi,
                                                       unsigned short* __restrict__ po)
{
    const int b = blockIdx.x;
    if (b < 96)       pack_body<D, D3 >(Wqkv, pq, b);
    else if (b < 224) pack_body<D, DFF>(W_in, pi, b - 96);
    else              pack_body<DFF, D>(W_out, po, b - 224);
}

// ---------------------------------------------------------------------------
// bf16 MFMA GEMM, both operands pre-packed fragment order. Direct global->
// VGPR operand loads (no LDS), explicit peeled double-buffer, 3 blocks/CU.
// Panel-colocating XCD swizzle. MFMA operands SWAPPED: D maps to row
// r = lane&15, cols n = (lane>>4)*4+t.
// EPI 0: qkv split -> q (cols<256) unscaled fp8 e4m3, k|v bf16 row-major
// EPI 1: bf16 C in fragment order [M/16][N/8][16][8] + fast exact gelu
// EPI 2: fp32 C row-major += Xadd, nontemporal f32x4 store
// ---------------------------------------------------------------------------
template <int EPI, int K, int N>
__global__ __launch_bounds__(256, 3) void mfma_gemm_kernel(const unsigned short* __restrict__ A,
                                                           const unsigned short* __restrict__ Bpk,
                                                           const float* __restrict__ bias,
                                                           void* __restrict__ Cout,
                                                           void* __restrict__ Cout2,
                                                           const float* __restrict__ Xadd)
{
    constexpr int C  = N / 128;          // col tiles
    constexpr int P  = M_PAD / 128;      // 313 row panels
    constexpr int NG = K / 32;           // MFMA k-groups (8 or 32, even)

    const int bid = blockIdx.x;
    const int xcd = bid & 7;
    const int t   = bid >> 3;
    const int c   = t % C;
    const int p   = (t / C) * 8 + xcd;
    if (p >= P) return;

    const int tid  = threadIdx.x;
    const int wave = tid >> 6;
    const int lane = tid & 63;
    const int row0 = p * 128;
    const int col0 = c * 128;
    const int wm   = (wave >> 1) * 64;
    const int wn   = (wave & 1) * 64;
    const int g    = lane >> 4;
    const int q    = lane & 15;

    f32x4 acc[4][4] = {};

    constexpr size_t tstride = (size_t)(K / 8) * 128;   // shorts per 16-row tile
    const unsigned short* pA = A   + ((size_t)((row0 + wm) >> 4) * (K / 8) + g) * 128 + q * 8;
    const unsigned short* pB = Bpk + ((size_t)((col0 + wn) >> 4) * (K / 8) + g) * 128 + q * 8;

    short8 aA[4], bA[4], aB[4], bB[4];
#pragma unroll
    for (int i = 0; i < 4; ++i) {      // group 0 -> buf A
        aA[i] = *reinterpret_cast<const short8*>(pA + i * tstride);
        bA[i] = *reinterpret_cast<const short8*>(pB + i * tstride);
    }
#pragma unroll
    for (int i = 0; i < 4; ++i) {      // group 1 -> buf B
        aB[i] = *reinterpret_cast<const short8*>(pA + i * tstride + 512);
        bB[i] = *reinterpret_cast<const short8*>(pB + i * tstride + 512);
    }

#pragma unroll 1
    for (int g2 = 0; g2 < NG / 2 - 1; ++g2) {
#pragma unroll
        for (int i = 0; i < 4; ++i)
#pragma unroll
            for (int j = 0; j < 4; ++j)
                acc[i][j] = __builtin_amdgcn_mfma_f32_16x16x32_bf16(bA[j], aA[i], acc[i][j], 0, 0, 0);
#pragma unroll
        for (int i = 0; i < 4; ++i) {  // group 2*g2+2 -> buf A
            aA[i] = *reinterpret_cast<const short8*>(pA + i * tstride + (size_t)(g2 * 8 + 8) * 128);
            bA[i] = *reinterpret_cast<const short8*>(pB + i * tstride + (size_t)(g2 * 8 + 8) * 128);
        }
#pragma unroll
        for (int i = 0; i < 4; ++i)
#pragma unroll
            for (int j = 0; j < 4; ++j)
                acc[i][j] = __builtin_amdgcn_mfma_f32_16x16x32_bf16(bB[j], aB[i], acc[i][j], 0, 0, 0);
#pragma unroll
        for (int i = 0; i < 4; ++i) {  // group 2*g2+3 -> buf B
            aB[i] = *reinterpret_cast<const short8*>(pA + i * tstride + (size_t)(g2 * 8 + 12) * 128);
            bB[i] = *reinterpret_cast<const short8*>(pB + i * tstride + (size_t)(g2 * 8 + 12) * 128);
        }
    }
#pragma unroll
    for (int i = 0; i < 4; ++i)
#pragma unroll
        for (int j = 0; j < 4; ++j)
            acc[i][j] = __builtin_amdgcn_mfma_f32_16x16x32_bf16(bA[j], aA[i], acc[i][j], 0, 0, 0);
#pragma unroll
    for (int i = 0; i < 4; ++i)
#pragma unroll
        for (int j = 0; j < 4; ++j)
            acc[i][j] = __builtin_amdgcn_mfma_f32_16x16x32_bf16(bB[j], aB[i], acc[i][j], 0, 0, 0);

    // Swapped D layout: r = row0+wm+i*16+q ; n = col0+wn+j*16+g*4+t (t=0..3)
    if constexpr (EPI == 0) {
        if (col0 < 256) {   // q columns -> fp8, UNSCALED (scale folded into k at attn)
            unsigned char* q8 = (unsigned char*)Cout;
#pragma unroll
            for (int j = 0; j < 4; ++j) {
                const int nb = col0 + wn + j * 16 + g * 4;
                const float4 bz = *reinterpret_cast<const float4*>(bias + nb);
#pragma unroll
                for (int i = 0; i < 4; ++i) {
                    const int r = row0 + wm + i * 16 + q;
                    if (r >= N_NODES) continue;
                    const unsigned int w = pack4_e4m3(acc[i][j][0] + bz.x, acc[i][j][1] + bz.y,
                                                      acc[i][j][2] + bz.z, acc[i][j][3] + bz.w);
                    *reinterpret_cast<unsigned int*>(q8 + (size_t)r * 256 + nb) = w;
                }
            }
        } else {            // k|v columns -> bf16 row-major [node][512]
            unsigned short* kv = (unsigned short*)Cout2;
#pragma unroll
            for (int j = 0; j < 4; ++j) {
                const int nb = col0 + wn + j * 16 + g * 4;
                const float4 bz = *reinterpret_cast<const float4*>(bias + nb);
#pragma unroll
                for (int i = 0; i < 4; ++i) {
                    const int r = row0 + wm + i * 16 + q;
                    if (r >= N_NODES) continue;
                    ushort4 u;
                    u.x = f2bf(acc[i][j][0] + bz.x);
                    u.y = f2bf(acc[i][j][1] + bz.y);
                    u.z = f2bf(acc[i][j][2] + bz.z);
                    u.w = f2bf(acc[i][j][3] + bz.w);
                    *reinterpret_cast<ushort4*>(kv + (size_t)r * 512 + (nb - 256)) = u;
                }
            }
        }
    } else if constexpr (EPI == 1) {
#pragma unroll
        for (int j = 0; j < 4; ++j) {
            const int nb = col0 + wn + j * 16 + g * 4;
            const float4 bz = *reinterpret_cast<const float4*>(bias + nb);
#pragma unroll
            for (int i = 0; i < 4; ++i) {
                const int r = row0 + wm + i * 16 + q;   // pad rows stored too (finite)
                const float o0 = fast_gelu(acc[i][j][0] + bz.x);
                const float o1 = fast_gelu(acc[i][j][1] + bz.y);
                const float o2 = fast_gelu(acc[i][j][2] + bz.z);
                const float o3 = fast_gelu(acc[i][j][3] + bz.w);
                const size_t off = (((size_t)(r >> 4) * (N / 8) + (nb >> 3)) * 16
                                    + (r & 15)) * 8 + (nb & 7);
                ushort4 u;
                u.x = f2bf(o0); u.y = f2bf(o1); u.z = f2bf(o2); u.w = f2bf(o3);
                *reinterpret_cast<ushort4*>((unsigned short*)Cout + off) = u;
            }
        }
    } else {
#pragma unroll
        for (int j = 0; j < 4; ++j) {
            const int nb = col0 + wn + j * 16 + g * 4;
            const float4 bz = *reinterpret_cast<const float4*>(bias + nb);
#pragma unroll
            for (int i = 0; i < 4; ++i) {
                const int r = row0 + wm + i * 16 + q;
                if (r >= N_NODES) continue;
                const float4 xd = *reinterpret_cast<const float4*>(Xadd + (size_t)r * N + nb);
                f32x4 ov;
                ov[0] = acc[i][j][0] + bz.x + xd.x;
                ov[1] = acc[i][j][1] + bz.y + xd.y;
                ov[2] = acc[i][j][2] + bz.z + xd.z;
                ov[3] = acc[i][j][3] + bz.w + xd.w;
                __builtin_nontemporal_store(ov,
                    reinterpret_cast<f32x4*>((float*)Cout + (size_t)r * N + nb));
            }
        }
    }
}

// ---------------------------------------------------------------------------
// CSR build
// ---------------------------------------------------------------------------
__global__ __launch_bounds__(256) void hist_kernel(const int* __restrict__ dst,
                                                   int* __restrict__ counts)
{
    const int i = blockIdx.x * 256 + threadIdx.x;
    atomicAdd(&counts[dst[i]], 1);
}

__global__ __launch_bounds__(1024) void scan_kernel(const int* __restrict__ counts,
                                                    int* __restrict__ rowptr,
                                                    int* __restrict__ cursor)
{
    const int PER = 40;
    const int tid  = threadIdx.x;
    const int base = tid * PER;
    int c[PER];
    int s = 0;
#pragma unroll
    for (int i = 0; i < PER; ++i) {
        const int idx = base + i;
        c[i] = (idx < N_NODES) ? counts[idx] : 0;
        s += c[i];
    }
    __shared__ int sm[1024];
    sm[tid] = s;
    __syncthreads();
    for (int off = 1; off < 1024; off <<= 1) {
        int t = (tid >= off) ? sm[tid - off] : 0;
        __syncthreads();
        sm[tid] += t;
        __syncthreads();
    }
    int run = sm[tid] - s;
#pragma unroll
    for (int i = 0; i < PER; ++i) {
        const int idx = base + i;
        if (idx < N_NODES) {
            rowptr[idx] = run;
            cursor[idx] = run;
            run += c[i];
        }
    }
    if (tid == 1023) rowptr[N_NODES] = sm[1023];
}

__global__ __launch_bounds__(256) void fill_kernel(const int* __restrict__ src,
                                                   const int* __restrict__ dst,
                                                   int* __restrict__ cursor,
                                                   int* __restrict__ srcs)
{
    const int e = blockIdx.x * 256 + threadIdx.x;
    const int pos = atomicAdd(&cursor[dst[e]], 1);
    if (pos >= 0 && pos < N_EDGES) srcs[pos] = src[e];
}

// ---------------------------------------------------------------------------
// Fused attention: q fp8 (256 B/row) + k|v bf16 (1024 B/row, pow2 stride).
// One wave per dst node; src list coalesce-prefetched, readlane broadcast,
// 4-edge unroll. k scaled by ATT_SCALE at load (q stored unscaled).
// Outputs: x fp32 row-major, xn bf16 in fragment order.
// ---------------------------------------------------------------------------
__global__ __launch_bounds__(256) void fused_attn_kernel(const unsigned char* __restrict__ qf8,
                                                         const unsigned short* __restrict__ kv,
                                                         const int* __restrict__ srcs,
                                                         const int* __restrict__ rowptr,
                                                         const float* __restrict__ triplet_h,
                                                         const float* __restrict__ g,
                                                         const float* __restrict__ b,
                                                         float* __restrict__ x,
                                                         unsigned short* __restrict__ xn)
{
    const int node = blockIdx.x * 4 + (threadIdx.x >> 6);
    const int lane = threadIdx.x & 63;
    int beg = rowptr[node];
    int end = rowptr[node + 1];
    beg = max(0, min(beg, N_EDGES));
    end = max(beg, min(end, N_EDGES));
    const int deg = end - beg;

    const ushort4 ku = *reinterpret_cast<const ushort4*>(
        kv + (size_t)node * 512 + lane * 4);
    const float k0 = bf2f(ku.x) * ATT_SCALE, k1 = bf2f(ku.y) * ATT_SCALE;
    const float k2 = bf2f(ku.z) * ATT_SCALE, k3 = bf2f(ku.w) * ATT_SCALE;

    float dsum = 0.0f;
    float4 acc = {0.0f, 0.0f, 0.0f, 0.0f};

    for (int base = 0; base < deg; base += 64) {
        const int cnt = min(64, deg - base);
        const int idx = base + lane;
        const int sv = (idx < deg) ? srcs[beg + idx] : 0;   // coalesced prefetch
        int j = 0;
        for (; j + 4 <= cnt; j += 4) {
            const int s0 = __builtin_amdgcn_readlane(sv, j);
            const int s1 = __builtin_amdgcn_readlane(sv, j + 1);
            const int s2 = __builtin_amdgcn_readlane(sv, j + 2);
            const int s3 = __builtin_amdgcn_readlane(sv, j + 3);
            const unsigned int qa = *reinterpret_cast<const unsigned int*>(qf8 + (size_t)s0 * 256 + lane * 4);
            const unsigned int qb = *reinterpret_cast<const unsigned int*>(qf8 + (size_t)s1 * 256 + lane * 4);
            const unsigned int qc = *reinterpret_cast<const unsigned int*>(qf8 + (size_t)s2 * 256 + lane * 4);
            const unsigned int qd = *reinterpret_cast<const unsigned int*>(qf8 + (size_t)s3 * 256 + lane * 4);
            const ushort4 va = *reinterpret_cast<const ushort4*>(kv + (size_t)s0 * 512 + 256 + lane * 4);
            const ushort4 vb = *reinterpret_cast<const ushort4*>(kv + (size_t)s1 * 512 + 256 + lane * 4);
            const ushort4 vc = *reinterpret_cast<const ushort4*>(kv + (size_t)s2 * 512 + 256 + lane * 4);
            const ushort4 vd = *reinterpret_cast<const ushort4*>(kv + (size_t)s3 * 512 + 256 + lane * 4);
            float a0, a1, a2, a3;
            dec4_e4m3(qa, a0, a1, a2, a3);
            float p0 = a0 * k0 + a1 * k1 + a2 * k2 + a3 * k3;
            dec4_e4m3(qb, a0, a1, a2, a3);
            float p1 = a0 * k0 + a1 * k1 + a2 * k2 + a3 * k3;
            dec4_e4m3(qc, a0, a1, a2, a3);
            float p2 = a0 * k0 + a1 * k1 + a2 * k2 + a3 * k3;
            dec4_e4m3(qd, a0, a1, a2, a3);
            float p3 = a0 * k0 + a1 * k1 + a2 * k2 + a3 * k3;
            p0 += __shfl_xor(p0, 1, 64); p1 += __shfl_xor(p1, 1, 64);
            p2 += __shfl_xor(p2, 1, 64); p3 += __shfl_xor(p3, 1, 64);
            p0 += __shfl_xor(p0, 2, 64); p1 += __shfl_xor(p1, 2, 64);
            p2 += __shfl_xor(p2, 2, 64); p3 += __shfl_xor(p3, 2, 64);
            p0 += __shfl_xor(p0, 4, 64); p1 += __shfl_xor(p1, 4, 64);
            p2 += __shfl_xor(p2, 4, 64); p3 += __shfl_xor(p3, 4, 64);
            const float w0 = __expf(p0), w1 = __expf(p1), w2 = __expf(p2), w3 = __expf(p3);
            acc.x += w0 * bf2f(va.x) + w1 * bf2f(vb.x) + w2 * bf2f(vc.x) + w3 * bf2f(vd.x);
            acc.y += w0 * bf2f(va.y) + w1 * bf2f(vb.y) + w2 * bf2f(vc.y) + w3 * bf2f(vd.y);
            acc.z += w0 * bf2f(va.z) + w1 * bf2f(vb.z) + w2 * bf2f(vc.z) + w3 * bf2f(vd.z);
            acc.w += w0 * bf2f(va.w) + w1 * bf2f(vb.w) + w2 * bf2f(vc.w) + w3 * bf2f(vd.w);
            dsum += (w0 + w1) + (w2 + w3);
        }
        for (; j < cnt; ++j) {
            const int s0 = __builtin_amdgcn_readlane(sv, j);
            const unsigned int qa = *reinterpret_cast<const unsigned int*>(qf8 + (size_t)s0 * 256 + lane * 4);
            const ushort4 va = *reinterpret_cast<const ushort4*>(kv + (size_t)s0 * 512 + 256 + lane * 4);
            float a0, a1, a2, a3;
            dec4_e4m3(qa, a0, a1, a2, a3);
            float p0 = a0 * k0 + a1 * k1 + a2 * k2 + a3 * k3;
            p0 += __shfl_xor(p0, 1, 64);
            p0 += __shfl_xor(p0, 2, 64);
            p0 += __shfl_xor(p0, 4, 64);
            const float w0 = __expf(p0);
            acc.x += w0 * bf2f(va.x);
            acc.y += w0 * bf2f(va.y);
            acc.z += w0 * bf2f(va.z);
            acc.w += w0 * bf2f(va.w);
            dsum += w0;
        }
    }
    const float inv = (deg > 0) ? 1.0f / dsum : 0.0f;

    const float4 th = *reinterpret_cast<const float4*>(
        triplet_h + (size_t)node * D + lane * 4);
    float4 xv;
    xv.x = th.x + acc.x * inv;
    xv.y = th.y + acc.y * inv;
    xv.z = th.z + acc.z * inv;
    xv.w = th.w + acc.w * inv;
    *reinterpret_cast<float4*>(x + (size_t)node * D + lane * 4) = xv;

    // LN2 across the wave
    float s  = xv.x + xv.y + xv.z + xv.w;
    float s2 = xv.x * xv.x + xv.y * xv.y + xv.z * xv.z + xv.w * xv.w;
#pragma unroll
    for (int o = 32; o > 0; o >>= 1) {
        s  += __shfl_xor(s,  o, 64);
        s2 += __shfl_xor(s2, o, 64);
    }
    const float mu  = s * (1.0f / D);
    const float var = s2 * (1.0f / D) - mu * mu;
    const float rs  = rsqrtf(var + LN_EPS);
    const float4 gg = *reinterpret_cast<const float4*>(g + lane * 4);
    const float4 bb = *reinterpret_cast<const float4*>(b + lane * 4);
    ushort4 o4;
    o4.x = f2bf((xv.x - mu) * rs * gg.x + bb.x);
    o4.y = f2bf((xv.y - mu) * rs * gg.y + bb.y);
    o4.z = f2bf((xv.z - mu) * rs * gg.z + bb.z);
    o4.w = f2bf((xv.w - mu) * rs * gg.w + bb.w);
    const size_t off = (((size_t)(node >> 4) * (D / 8) + (lane >> 1)) * 16 + (node & 15)) * 8
                       + (lane & 1) * 4;
    *reinterpret_cast<ushort4*>(xn + off) = o4;
}

// ---------------------------------------------------------------------------
extern "C" void kernel_launch(void* const* d_in, const int* in_sizes, int n_in,
                              void* d_out, int out_size, void* d_ws, size_t ws_size,
                              hipStream_t stream)
{
    const float* triplet_h = (const float*)d_in[0];
    const int*   src       = (const int*)d_in[1];
    const int*   dst       = (const int*)d_in[2];
    const float* Wqkv      = (const float*)d_in[3];
    const float* bqkv      = (const float*)d_in[4];
    const float* ln_attn_g = (const float*)d_in[5];
    const float* ln_attn_b = (const float*)d_in[6];
    const float* ln_res_g  = (const float*)d_in[7];
    const float* ln_res_b  = (const float*)d_in[8];
    const float* W_in      = (const float*)d_in[9];
    const float* b_in      = (const float*)d_in[10];
    const float* W_out     = (const float*)d_in[11];
    const float* b_out     = (const float*)d_in[12];
    float* out = (float*)d_out;

    // Workspace (~162 MB, under 245.76 MB ceiling):
    char* w = (char*)d_ws;
    unsigned short* bufA = (unsigned short*)w;   // kv bf16 row-major OR a1 bf16 frag
    w += (size_t)M_PAD * DFF * sizeof(unsigned short);
    unsigned short* h_xn = (unsigned short*)w;  w += (size_t)M_PAD * D * sizeof(unsigned short);
    float*          x    = (float*)w;           w += (size_t)N_NODES * D * sizeof(float);
    unsigned char*  qf8  = (unsigned char*)w;   w += (size_t)N_NODES * 256;
    unsigned short* Wqkv_pk = (unsigned short*)w; w += (size_t)D * D3 * sizeof(unsigned short);
    unsigned short* Win_pk  = (unsigned short*)w; w += (size_t)D * DFF * sizeof(unsigned short);
    unsigned short* Wout_pk = (unsigned short*)w; w += (size_t)DFF * D * sizeof(unsigned short);
    int* counts = (int*)w;  w += (size_t)N_NODES * sizeof(int);
    int* rowptr = (int*)w;  w += (size_t)(N_NODES + 1) * sizeof(int);
    int* cursor = (int*)w;  w += (size_t)N_NODES * sizeof(int);
    int* srcs   = (int*)w;  w += (size_t)N_EDGES * sizeof(int);

    unsigned short* kv = bufA;  // [40000][512] bf16 (k|v), dead after fused_attn
    unsigned short* a1 = bufA;  // [M_PAD/16][128][16][8] bf16 frag, live FFN only

    // ---- CSR build ----
    (void)hipMemsetAsync(counts, 0, (size_t)N_NODES * sizeof(int), stream);
    hist_kernel<<<N_EDGES / 256, 256, 0, stream>>>(dst, counts);
    scan_kernel<<<1, 1024, 0, stream>>>(counts, rowptr, cursor);
    fill_kernel<<<N_EDGES / 256, 256, 0, stream>>>(src, dst, cursor, srcs);

    // ---- weight packing (one launch) ----
    pack_all_kernel<<<352, 256, 0, stream>>>(Wqkv, W_in, W_out, Wqkv_pk, Win_pk, Wout_pk);

    // ---- main pipeline ----
    ln_bf_kernel<<<M_PAD / 4, 256, 0, stream>>>(triplet_h, ln_attn_g, ln_attn_b, h_xn);
    mfma_gemm_kernel<0, D, D3><<<((M_PAD / 128 + 7) / 8) * 8 * (D3 / 128), 256, 0, stream>>>(
        h_xn, Wqkv_pk, bqkv, qf8, kv, nullptr);
    fused_attn_kernel<<<N_NODES / 4, 256, 0, stream>>>(qf8, kv, srcs, rowptr, triplet_h,
                                                       ln_res_g, ln_res_b, x, h_xn);
    // kv dead; a1 overwrites it (EPI1 stores pad rows too -> no memset needed)
    mfma_gemm_kernel<1, D, DFF><<<((M_PAD / 128 + 7) / 8) * 8 * (DFF / 128), 256, 0, stream>>>(
        h_xn, Win_pk, b_in, a1, nullptr, nullptr);
    mfma_gemm_kernel<2, DFF, D><<<((M_PAD / 128 + 7) / 8) * 8 * (D / 128), 256, 0, stream>>>(
        a1, Wout_pk, b_out, out, nullptr, x);

    (void)in_sizes; (void)n_in; (void)out_size; (void)ws_size;
}

// Round 5
// 444.508 us; speedup vs baseline: 1.2987x; 1.0070x over previous
//
#include <hip/hip_runtime.h>
#include <math.h>

#define N_NODES 40000
#define M_PAD   40064      // 313 * 128
#define N_EDGES 640000
#define D       256
#define H       8
#define DFF     1024
#define D3      768
#define ATT_SCALE 0.0625f  // 256^-0.5
#define LN_EPS  1e-5f

typedef __attribute__((ext_vector_type(8))) short short8;
typedef __attribute__((ext_vector_type(4))) float f32x4;
typedef __attribute__((ext_vector_type(2))) float f32x2;

__device__ __forceinline__ unsigned short f2bf(float f) {
    unsigned int u = __builtin_bit_cast(unsigned int, f);
    u = (u + 0x7FFF + ((u >> 16) & 1)) >> 16;   // RTNE
    return (unsigned short)u;
}
__device__ __forceinline__ float bf2f(unsigned short u) {
    return __builtin_bit_cast(float, (unsigned int)u << 16);
}

// Fast exact-gelu: Abramowitz-Stegun 7.1.26 erf (|eps| <= 1.5e-7, branchless).
__device__ __forceinline__ float fast_gelu(float x) {
    const float z  = fabsf(x) * 0.70710678118654752f;
    const float t  = __builtin_amdgcn_rcpf(1.0f + 0.3275911f * z);
    float p = 1.061405429f;
    p = p * t - 1.453152027f;
    p = p * t + 1.421413741f;
    p = p * t - 0.284496736f;
    p = p * t + 0.254829592f;
    const float e  = __expf(-z * z);
    const float ea = 1.0f - p * t * e;          // erf(|x|/sqrt2)
    const float er = (x < 0.0f) ? -ea : ea;
    return 0.5f * x * (1.0f + er);
}

#define GLOAD_LDS16(g, l) \
    __builtin_amdgcn_global_load_lds((const __attribute__((address_space(1))) void*)(g), \
                                     (__attribute__((address_space(3))) void*)(l), 16, 0, 0)

// ---------------- fp8 e4m3 pack/unpack (HW cvt on gfx950, SW fallback) -----
#if __has_builtin(__builtin_amdgcn_cvt_pk_fp8_f32) && __has_builtin(__builtin_amdgcn_cvt_pk_f32_fp8)
#define HW_FP8 1
#else
#define HW_FP8 0
__device__ __forceinline__ unsigned char enc_e4m3(float f) {
    unsigned int u = __builtin_bit_cast(unsigned int, f);
    unsigned int s = (u >> 24) & 0x80;
    float a = fabsf(f);
    if (a >= 0x1p-6f) {
        unsigned int bits = __builtin_bit_cast(unsigned int, a);
        unsigned int q = bits >> 20;
        unsigned int rem = bits & 0xFFFFFu;
        q += (rem > 0x80000u) || ((rem == 0x80000u) && (q & 1));
        q -= 960;                          // rebias (120<<3)
        if (q > 126) q = 126;              // clamp to 448
        return (unsigned char)(s | q);
    }
    float t = a * 512.0f;
    unsigned int r = (unsigned int)rintf(t);   // RNE; 8 -> min normal naturally
    return (unsigned char)(s | r);
}
__device__ __forceinline__ float dec_e4m3(unsigned int v) {
    unsigned int em = v & 0x7f;
    float n = __builtin_bit_cast(float, (em << 20) + 0x3C000000u);
    float r = (em >= 8) ? n : (float)em * 0x1p-9f;
    return (v & 0x80) ? -r : r;
}
#endif

__device__ __forceinline__ unsigned int pack4_e4m3(float a, float b, float c, float d) {
#if HW_FP8
    unsigned int w = (unsigned int)__builtin_amdgcn_cvt_pk_fp8_f32(a, b, 0, false);
    w = (unsigned int)__builtin_amdgcn_cvt_pk_fp8_f32(c, d, (int)w, true);
    return w;
#else
    return (unsigned int)enc_e4m3(a) | ((unsigned int)enc_e4m3(b) << 8)
         | ((unsigned int)enc_e4m3(c) << 16) | ((unsigned int)enc_e4m3(d) << 24);
#endif
}
__device__ __forceinline__ void dec4_e4m3(unsigned int w, float& a, float& b, float& c, float& d) {
#if HW_FP8
    f32x2 lo = __builtin_amdgcn_cvt_pk_f32_fp8((int)w, false);
    f32x2 hi = __builtin_amdgcn_cvt_pk_f32_fp8((int)w, true);
    a = lo[0]; b = lo[1]; c = hi[0]; d = hi[1];
#else
    a = dec_e4m3(w & 0xff); b = dec_e4m3((w >> 8) & 0xff);
    c = dec_e4m3((w >> 16) & 0xff); d = dec_e4m3(w >> 24);
#endif
}

// ---------------------------------------------------------------------------
// LayerNorm -> bf16 output in MFMA A-fragment order [M/16][D/8][16][8].
// Covers pad rows [N_NODES, M_PAD) with zeros (replaces a memset).
// ---------------------------------------------------------------------------
__global__ __launch_bounds__(256) void ln_bf_kernel(const float* __restrict__ in,
                                                    const float* __restrict__ g,
                                                    const float* __restrict__ b,
                                                    unsigned short* __restrict__ out)
{
    const int row  = blockIdx.x * 4 + (threadIdx.x >> 6);
    const int lane = threadIdx.x & 63;
    const size_t off = (((size_t)(row >> 4) * (D / 8) + (lane >> 1)) * 16 + (row & 15)) * 8
                       + (lane & 1) * 4;
    if (row >= N_NODES) {
        ushort4 z = {0, 0, 0, 0};
        *reinterpret_cast<ushort4*>(out + off) = z;
        return;
    }
    const float4 v = *reinterpret_cast<const float4*>(in + (size_t)row * D + lane * 4);
    float s  = v.x + v.y + v.z + v.w;
    float s2 = v.x * v.x + v.y * v.y + v.z * v.z + v.w * v.w;
#pragma unroll
    for (int o = 32; o > 0; o >>= 1) {
        s  += __shfl_xor(s,  o, 64);
        s2 += __shfl_xor(s2, o, 64);
    }
    const float mu  = s * (1.0f / D);
    const float var = s2 * (1.0f / D) - mu * mu;
    const float rs  = rsqrtf(var + LN_EPS);
    const float4 gg = *reinterpret_cast<const float4*>(g + lane * 4);
    const float4 bb = *reinterpret_cast<const float4*>(b + lane * 4);
    ushort4 o4;
    o4.x = f2bf((v.x - mu) * rs * gg.x + bb.x);
    o4.y = f2bf((v.y - mu) * rs * gg.y + bb.y);
    o4.z = f2bf((v.z - mu) * rs * gg.z + bb.z);
    o4.w = f2bf((v.w - mu) * rs * gg.w + bb.w);
    *reinterpret_cast<ushort4*>(out + off) = o4;
}

// ---------------------------------------------------------------------------
// Weight pack: W[K][N] fp32 -> bf16 packed [N/16][K/8][16][8]. All three
// weights in ONE kernel (one launch).
// ---------------------------------------------------------------------------
template <int K, int N>
__device__ __forceinline__ void pack_body(const float* __restrict__ W,
                                          unsigned short* __restrict__ Wpk, int blk)
{
    const int idx = blk * 256 + threadIdx.x;   // [N/16][K/8][16]
    const int ni  = idx & 15;
    const int kc  = (idx >> 4) % (K / 8);
    const int nt  = idx / (16 * (K / 8));
    const int n   = nt * 16 + ni;
    unsigned short o[8];
#pragma unroll
    for (int i = 0; i < 8; ++i)
        o[i] = f2bf(W[(size_t)(kc * 8 + i) * N + n]);
    *reinterpret_cast<short8*>(Wpk + (size_t)idx * 8) = *reinterpret_cast<short8*>(o);
}

__global__ __launch_bounds__(256) void pack_all_kernel(const float* __restrict__ Wqkv,
                                                       const float* __restrict__ W_in,
                                                       const float* __restrict__ W_out,
                                                       unsigned short* __restrict__ pq,
                                                       unsigned short* __restrict__ pi,
                                                       unsigned short* __restrict__ po)
{
    const int b = blockIdx.x;
    if (b < 96)       pack_body<D, D3 >(Wqkv, pq, b);
    else if (b < 224) pack_body<D, DFF>(W_in, pi, b - 96);
    else              pack_body<DFF, D>(W_out, po, b - 224);
}

// ---------------------------------------------------------------------------
// bf16 MFMA GEMM -- m97-verified staging structure (128x128 tile, 4 waves,
// BK=32, global_load_lds width 16, barrier-synced K loop) merged with the
// proven vectorized epilogues. LDS 16 KB; ~110 regs -> 4 blocks/CU via
// __launch_bounds__(256,4). Staging shares fragments block-wide (no 2x
// per-wave duplication of the reg-direct scheme).
// Panel-colocating XCD swizzle. MFMA operands SWAPPED: D maps to row
// r = lane&15, cols n = (lane>>4)*4+t -> 4 consecutive cols per thread.
// EPI 0: qkv split -> q (cols<256) unscaled fp8 e4m3, k|v bf16 row-major
// EPI 1: bf16 C in fragment order [M/16][N/8][16][8] + fast exact gelu
// EPI 2: fp32 C row-major += Xadd, nontemporal f32x4 store
// ---------------------------------------------------------------------------
template <int EPI, int K, int N>
__global__ __launch_bounds__(256, 4) void mfma_gemm_kernel(const unsigned short* __restrict__ A,
                                                           const unsigned short* __restrict__ Bpk,
                                                           const float* __restrict__ bias,
                                                           void* __restrict__ Cout,
                                                           void* __restrict__ Cout2,
                                                           const float* __restrict__ Xadd)
{
    constexpr int C = N / 128;           // col tiles
    constexpr int P = M_PAD / 128;       // 313 row panels

    const int bid = blockIdx.x;
    const int xcd = bid & 7;
    const int t   = bid >> 3;
    const int c   = t % C;
    const int p   = (t / C) * 8 + xcd;
    if (p >= P) return;

    __shared__ unsigned short As[4096];   // [mt8][kc4][16][8] = 8 KB
    __shared__ unsigned short Bs[4096];

    const int tid  = threadIdx.x;
    const int wave = tid >> 6;
    const int lane = tid & 63;
    const int row0 = p * 128;
    const int col0 = c * 128;
    const int wm   = (wave >> 1) * 64;
    const int wn   = (wave & 1) * 64;
    const int g    = lane >> 4;
    const int q    = lane & 15;

    f32x4 acc[4][4] = {};

    const int fragoff = g * 128 + q * 8;

    for (int k0 = 0; k0 < K; k0 += 32) {
        const int kq = k0 >> 3;   // k-chunk index (K/8 units)
        // Each wave DMAs 2 A-chunks + 2 B-chunks of 1 KB (64 lanes x 16 B).
#pragma unroll
        for (int cc = 0; cc < 2; ++cc) {
            const int mt = wave * 2 + cc;                // 0..7
            const unsigned short* gA =
                A + ((size_t)(row0 / 16 + mt) * (K / 8) + kq) * 128 + lane * 8;
            GLOAD_LDS16(gA, &As[mt * 512]);
            const unsigned short* gB =
                Bpk + ((size_t)(col0 / 16 + mt) * (K / 8) + kq) * 128 + lane * 8;
            GLOAD_LDS16(gB, &Bs[mt * 512]);
        }
        __syncthreads();

        short8 af[4], bf[4];
#pragma unroll
        for (int i = 0; i < 4; ++i) {
            af[i] = *reinterpret_cast<const short8*>(&As[(wm / 16 + i) * 512 + fragoff]);
            bf[i] = *reinterpret_cast<const short8*>(&Bs[(wn / 16 + i) * 512 + fragoff]);
        }
#pragma unroll
        for (int i = 0; i < 4; ++i)
#pragma unroll
            for (int j = 0; j < 4; ++j)
                acc[i][j] = __builtin_amdgcn_mfma_f32_16x16x32_bf16(bf[j], af[i], acc[i][j], 0, 0, 0);
        __syncthreads();
    }

    // Swapped D layout: r = row0+wm+i*16+q ; n = col0+wn+j*16+g*4+t (t=0..3)
    if constexpr (EPI == 0) {
        if (col0 < 256) {   // q columns -> fp8, UNSCALED (scale folded into k at attn)
            unsigned char* q8 = (unsigned char*)Cout;
#pragma unroll
            for (int j = 0; j < 4; ++j) {
                const int nb = col0 + wn + j * 16 + g * 4;
                const float4 bz = *reinterpret_cast<const float4*>(bias + nb);
#pragma unroll
                for (int i = 0; i < 4; ++i) {
                    const int r = row0 + wm + i * 16 + q;
                    if (r >= N_NODES) continue;
                    const unsigned int w = pack4_e4m3(acc[i][j][0] + bz.x, acc[i][j][1] + bz.y,
                                                      acc[i][j][2] + bz.z, acc[i][j][3] + bz.w);
                    *reinterpret_cast<unsigned int*>(q8 + (size_t)r * 256 + nb) = w;
                }
            }
        } else {            // k|v columns -> bf16 row-major [node][512]
            unsigned short* kv = (unsigned short*)Cout2;
#pragma unroll
            for (int j = 0; j < 4; ++j) {
                const int nb = col0 + wn + j * 16 + g * 4;
                const float4 bz = *reinterpret_cast<const float4*>(bias + nb);
#pragma unroll
                for (int i = 0; i < 4; ++i) {
                    const int r = row0 + wm + i * 16 + q;
                    if (r >= N_NODES) continue;
                    ushort4 u;
                    u.x = f2bf(acc[i][j][0] + bz.x);
                    u.y = f2bf(acc[i][j][1] + bz.y);
                    u.z = f2bf(acc[i][j][2] + bz.z);
                    u.w = f2bf(acc[i][j][3] + bz.w);
                    *reinterpret_cast<ushort4*>(kv + (size_t)r * 512 + (nb - 256)) = u;
                }
            }
        }
    } else if constexpr (EPI == 1) {
#pragma unroll
        for (int j = 0; j < 4; ++j) {
            const int nb = col0 + wn + j * 16 + g * 4;
            const float4 bz = *reinterpret_cast<const float4*>(bias + nb);
#pragma unroll
            for (int i = 0; i < 4; ++i) {
                const int r = row0 + wm + i * 16 + q;   // pad rows stored too (finite)
                const float o0 = fast_gelu(acc[i][j][0] + bz.x);
                const float o1 = fast_gelu(acc[i][j][1] + bz.y);
                const float o2 = fast_gelu(acc[i][j][2] + bz.z);
                const float o3 = fast_gelu(acc[i][j][3] + bz.w);
                const size_t off = (((size_t)(r >> 4) * (N / 8) + (nb >> 3)) * 16
                                    + (r & 15)) * 8 + (nb & 7);
                ushort4 u;
                u.x = f2bf(o0); u.y = f2bf(o1); u.z = f2bf(o2); u.w = f2bf(o3);
                *reinterpret_cast<ushort4*>((unsigned short*)Cout + off) = u;
            }
        }
    } else {
#pragma unroll
        for (int j = 0; j < 4; ++j) {
            const int nb = col0 + wn + j * 16 + g * 4;
            const float4 bz = *reinterpret_cast<const float4*>(bias + nb);
#pragma unroll
            for (int i = 0; i < 4; ++i) {
                const int r = row0 + wm + i * 16 + q;
                if (r >= N_NODES) continue;
                const float4 xd = *reinterpret_cast<const float4*>(Xadd + (size_t)r * N + nb);
                f32x4 ov;
                ov[0] = acc[i][j][0] + bz.x + xd.x;
                ov[1] = acc[i][j][1] + bz.y + xd.y;
                ov[2] = acc[i][j][2] + bz.z + xd.z;
                ov[3] = acc[i][j][3] + bz.w + xd.w;
                __builtin_nontemporal_store(ov,
                    reinterpret_cast<f32x4*>((float*)Cout + (size_t)r * N + nb));
            }
        }
    }
}

// ---------------------------------------------------------------------------
// CSR build
// ---------------------------------------------------------------------------
__global__ __launch_bounds__(256) void hist_kernel(const int* __restrict__ dst,
                                                   int* __restrict__ counts)
{
    const int i = blockIdx.x * 256 + threadIdx.x;
    atomicAdd(&counts[dst[i]], 1);
}

__global__ __launch_bounds__(1024) void scan_kernel(const int* __restrict__ counts,
                                                    int* __restrict__ rowptr,
                                                    int* __restrict__ cursor)
{
    const int PER = 40;
    const int tid  = threadIdx.x;
    const int base = tid * PER;
    int c[PER];
    int s = 0;
#pragma unroll
    for (int i = 0; i < PER; ++i) {
        const int idx = base + i;
        c[i] = (idx < N_NODES) ? counts[idx] : 0;
        s += c[i];
    }
    __shared__ int sm[1024];
    sm[tid] = s;
    __syncthreads();
    for (int off = 1; off < 1024; off <<= 1) {
        int t = (tid >= off) ? sm[tid - off] : 0;
        __syncthreads();
        sm[tid] += t;
        __syncthreads();
    }
    int run = sm[tid] - s;
#pragma unroll
    for (int i = 0; i < PER; ++i) {
        const int idx = base + i;
        if (idx < N_NODES) {
            rowptr[idx] = run;
            cursor[idx] = run;
            run += c[i];
        }
    }
    if (tid == 1023) rowptr[N_NODES] = sm[1023];
}

__global__ __launch_bounds__(256) void fill_kernel(const int* __restrict__ src,
                                                   const int* __restrict__ dst,
                                                   int* __restrict__ cursor,
                                                   int* __restrict__ srcs)
{
    const int e = blockIdx.x * 256 + threadIdx.x;
    const int pos = atomicAdd(&cursor[dst[e]], 1);
    if (pos >= 0 && pos < N_EDGES) srcs[pos] = src[e];
}

// ---------------------------------------------------------------------------
// Fused attention: q fp8 (256 B/row) + k|v bf16 (1024 B/row, pow2 stride).
// One wave per dst node; src list coalesce-prefetched, readlane broadcast,
// 4-edge unroll. k scaled by ATT_SCALE at load (q stored unscaled).
// Outputs: x fp32 row-major, xn bf16 in fragment order.
// ---------------------------------------------------------------------------
__global__ __launch_bounds__(256) void fused_attn_kernel(const unsigned char* __restrict__ qf8,
                                                         const unsigned short* __restrict__ kv,
                                                         const int* __restrict__ srcs,
                                                         const int* __restrict__ rowptr,
                                                         const float* __restrict__ triplet_h,
                                                         const float* __restrict__ g,
                                                         const float* __restrict__ b,
                                                         float* __restrict__ x,
                                                         unsigned short* __restrict__ xn)
{
    const int node = blockIdx.x * 4 + (threadIdx.x >> 6);
    const int lane = threadIdx.x & 63;
    int beg = rowptr[node];
    int end = rowptr[node + 1];
    beg = max(0, min(beg, N_EDGES));
    end = max(beg, min(end, N_EDGES));
    const int deg = end - beg;

    const ushort4 ku = *reinterpret_cast<const ushort4*>(
        kv + (size_t)node * 512 + lane * 4);
    const float k0 = bf2f(ku.x) * ATT_SCALE, k1 = bf2f(ku.y) * ATT_SCALE;
    const float k2 = bf2f(ku.z) * ATT_SCALE, k3 = bf2f(ku.w) * ATT_SCALE;

    float dsum = 0.0f;
    float4 acc = {0.0f, 0.0f, 0.0f, 0.0f};

    for (int base = 0; base < deg; base += 64) {
        const int cnt = min(64, deg - base);
        const int idx = base + lane;
        const int sv = (idx < deg) ? srcs[beg + idx] : 0;   // coalesced prefetch
        int j = 0;
        for (; j + 4 <= cnt; j += 4) {
            const int s0 = __builtin_amdgcn_readlane(sv, j);
            const int s1 = __builtin_amdgcn_readlane(sv, j + 1);
            const int s2 = __builtin_amdgcn_readlane(sv, j + 2);
            const int s3 = __builtin_amdgcn_readlane(sv, j + 3);
            const unsigned int qa = *reinterpret_cast<const unsigned int*>(qf8 + (size_t)s0 * 256 + lane * 4);
            const unsigned int qb = *reinterpret_cast<const unsigned int*>(qf8 + (size_t)s1 * 256 + lane * 4);
            const unsigned int qc = *reinterpret_cast<const unsigned int*>(qf8 + (size_t)s2 * 256 + lane * 4);
            const unsigned int qd = *reinterpret_cast<const unsigned int*>(qf8 + (size_t)s3 * 256 + lane * 4);
            const ushort4 va = *reinterpret_cast<const ushort4*>(kv + (size_t)s0 * 512 + 256 + lane * 4);
            const ushort4 vb = *reinterpret_cast<const ushort4*>(kv + (size_t)s1 * 512 + 256 + lane * 4);
            const ushort4 vc = *reinterpret_cast<const ushort4*>(kv + (size_t)s2 * 512 + 256 + lane * 4);
            const ushort4 vd = *reinterpret_cast<const ushort4*>(kv + (size_t)s3 * 512 + 256 + lane * 4);
            float a0, a1, a2, a3;
            dec4_e4m3(qa, a0, a1, a2, a3);
            float p0 = a0 * k0 + a1 * k1 + a2 * k2 + a3 * k3;
            dec4_e4m3(qb, a0, a1, a2, a3);
            float p1 = a0 * k0 + a1 * k1 + a2 * k2 + a3 * k3;
            dec4_e4m3(qc, a0, a1, a2, a3);
            float p2 = a0 * k0 + a1 * k1 + a2 * k2 + a3 * k3;
            dec4_e4m3(qd, a0, a1, a2, a3);
            float p3 = a0 * k0 + a1 * k1 + a2 * k2 + a3 * k3;
            p0 += __shfl_xor(p0, 1, 64); p1 += __shfl_xor(p1, 1, 64);
            p2 += __shfl_xor(p2, 1, 64); p3 += __shfl_xor(p3, 1, 64);
            p0 += __shfl_xor(p0, 2, 64); p1 += __shfl_xor(p1, 2, 64);
            p2 += __shfl_xor(p2, 2, 64); p3 += __shfl_xor(p3, 2, 64);
            p0 += __shfl_xor(p0, 4, 64); p1 += __shfl_xor(p1, 4, 64);
            p2 += __shfl_xor(p2, 4, 64); p3 += __shfl_xor(p3, 4, 64);
            const float w0 = __expf(p0), w1 = __expf(p1), w2 = __expf(p2), w3 = __expf(p3);
            acc.x += w0 * bf2f(va.x) + w1 * bf2f(vb.x) + w2 * bf2f(vc.x) + w3 * bf2f(vd.x);
            acc.y += w0 * bf2f(va.y) + w1 * bf2f(vb.y) + w2 * bf2f(vc.y) + w3 * bf2f(vd.y);
            acc.z += w0 * bf2f(va.z) + w1 * bf2f(vb.z) + w2 * bf2f(vc.z) + w3 * bf2f(vd.z);
            acc.w += w0 * bf2f(va.w) + w1 * bf2f(vb.w) + w2 * bf2f(vc.w) + w3 * bf2f(vd.w);
            dsum += (w0 + w1) + (w2 + w3);
        }
        for (; j < cnt; ++j) {
            const int s0 = __builtin_amdgcn_readlane(sv, j);
            const unsigned int qa = *reinterpret_cast<const unsigned int*>(qf8 + (size_t)s0 * 256 + lane * 4);
            const ushort4 va = *reinterpret_cast<const ushort4*>(kv + (size_t)s0 * 512 + 256 + lane * 4);
            float a0, a1, a2, a3;
            dec4_e4m3(qa, a0, a1, a2, a3);
            float p0 = a0 * k0 + a1 * k1 + a2 * k2 + a3 * k3;
            p0 += __shfl_xor(p0, 1, 64);
            p0 += __shfl_xor(p0, 2, 64);
            p0 += __shfl_xor(p0, 4, 64);
            const float w0 = __expf(p0);
            acc.x += w0 * bf2f(va.x);
            acc.y += w0 * bf2f(va.y);
            acc.z += w0 * bf2f(va.z);
            acc.w += w0 * bf2f(va.w);
            dsum += w0;
        }
    }
    const float inv = (deg > 0) ? 1.0f / dsum : 0.0f;

    const float4 th = *reinterpret_cast<const float4*>(
        triplet_h + (size_t)node * D + lane * 4);
    float4 xv;
    xv.x = th.x + acc.x * inv;
    xv.y = th.y + acc.y * inv;
    xv.z = th.z + acc.z * inv;
    xv.w = th.w + acc.w * inv;
    *reinterpret_cast<float4*>(x + (size_t)node * D + lane * 4) = xv;

    // LN2 across the wave
    float s  = xv.x + xv.y + xv.z + xv.w;
    float s2 = xv.x * xv.x + xv.y * xv.y + xv.z * xv.z + xv.w * xv.w;
#pragma unroll
    for (int o = 32; o > 0; o >>= 1) {
        s  += __shfl_xor(s,  o, 64);
        s2 += __shfl_xor(s2, o, 64);
    }
    const float mu  = s * (1.0f / D);
    const float var = s2 * (1.0f / D) - mu * mu;
    const float rs  = rsqrtf(var + LN_EPS);
    const float4 gg = *reinterpret_cast<const float4*>(g + lane * 4);
    const float4 bb = *reinterpret_cast<const float4*>(b + lane * 4);
    ushort4 o4;
    o4.x = f2bf((xv.x - mu) * rs * gg.x + bb.x);
    o4.y = f2bf((xv.y - mu) * rs * gg.y + bb.y);
    o4.z = f2bf((xv.z - mu) * rs * gg.z + bb.z);
    o4.w = f2bf((xv.w - mu) * rs * gg.w + bb.w);
    const size_t off = (((size_t)(node >> 4) * (D / 8) + (lane >> 1)) * 16 + (node & 15)) * 8
                       + (lane & 1) * 4;
    *reinterpret_cast<ushort4*>(xn + off) = o4;
}

// ---------------------------------------------------------------------------
extern "C" void kernel_launch(void* const* d_in, const int* in_sizes, int n_in,
                              void* d_out, int out_size, void* d_ws, size_t ws_size,
                              hipStream_t stream)
{
    const float* triplet_h = (const float*)d_in[0];
    const int*   src       = (const int*)d_in[1];
    const int*   dst       = (const int*)d_in[2];
    const float* Wqkv      = (const float*)d_in[3];
    const float* bqkv      = (const float*)d_in[4];
    const float* ln_attn_g = (const float*)d_in[5];
    const float* ln_attn_b = (const float*)d_in[6];
    const float* ln_res_g  = (const float*)d_in[7];
    const float* ln_res_b  = (const float*)d_in[8];
    const float* W_in      = (const float*)d_in[9];
    const float* b_in      = (const float*)d_in[10];
    const float* W_out     = (const float*)d_in[11];
    const float* b_out     = (const float*)d_in[12];
    float* out = (float*)d_out;

    // Workspace (~162 MB, under 245.76 MB ceiling):
    char* w = (char*)d_ws;
    unsigned short* bufA = (unsigned short*)w;   // kv bf16 row-major OR a1 bf16 frag
    w += (size_t)M_PAD * DFF * sizeof(unsigned short);
    unsigned short* h_xn = (unsigned short*)w;  w += (size_t)M_PAD * D * sizeof(unsigned short);
    float*          x    = (float*)w;           w += (size_t)N_NODES * D * sizeof(float);
    unsigned char*  qf8  = (unsigned char*)w;   w += (size_t)N_NODES * 256;
    unsigned short* Wqkv_pk = (unsigned short*)w; w += (size_t)D * D3 * sizeof(unsigned short);
    unsigned short* Win_pk  = (unsigned short*)w; w += (size_t)D * DFF * sizeof(unsigned short);
    unsigned short* Wout_pk = (unsigned short*)w; w += (size_t)DFF * D * sizeof(unsigned short);
    int* counts = (int*)w;  w += (size_t)N_NODES * sizeof(int);
    int* rowptr = (int*)w;  w += (size_t)(N_NODES + 1) * sizeof(int);
    int* cursor = (int*)w;  w += (size_t)N_NODES * sizeof(int);
    int* srcs   = (int*)w;  w += (size_t)N_EDGES * sizeof(int);

    unsigned short* kv = bufA;  // [40000][512] bf16 (k|v), dead after fused_attn
    unsigned short* a1 = bufA;  // [M_PAD/16][128][16][8] bf16 frag, live FFN only

    // ---- CSR build ----
    (void)hipMemsetAsync(counts, 0, (size_t)N_NODES * sizeof(int), stream);
    hist_kernel<<<N_EDGES / 256, 256, 0, stream>>>(dst, counts);
    scan_kernel<<<1, 1024, 0, stream>>>(counts, rowptr, cursor);
    fill_kernel<<<N_EDGES / 256, 256, 0, stream>>>(src, dst, cursor, srcs);

    // ---- weight packing (one launch) ----
    pack_all_kernel<<<352, 256, 0, stream>>>(Wqkv, W_in, W_out, Wqkv_pk, Win_pk, Wout_pk);

    // ---- main pipeline ----
    ln_bf_kernel<<<M_PAD / 4, 256, 0, stream>>>(triplet_h, ln_attn_g, ln_attn_b, h_xn);
    mfma_gemm_kernel<0, D, D3><<<((M_PAD / 128 + 7) / 8) * 8 * (D3 / 128), 256, 0, stream>>>(
        h_xn, Wqkv_pk, bqkv, qf8, kv, nullptr);
    fused_attn_kernel<<<N_NODES / 4, 256, 0, stream>>>(qf8, kv, srcs, rowptr, triplet_h,
                                                       ln_res_g, ln_res_b, x, h_xn);
    // kv dead; a1 overwrites it (EPI1 stores pad rows too -> no memset needed)
    mfma_gemm_kernel<1, D, DFF><<<((M_PAD / 128 + 7) / 8) * 8 * (DFF / 128), 256, 0, stream>>>(
        h_xn, Win_pk, b_in, a1, nullptr, nullptr);
    mfma_gemm_kernel<2, DFF, D><<<((M_PAD / 128 + 7) / 8) * 8 * (D / 128), 256, 0, stream>>>(
        a1, Wout_pk, b_out, out, nullptr, x);

    (void)in_sizes; (void)n_in; (void)out_size; (void)ws_size;
}